// Round 3
// baseline (537.323 us; speedup 1.0000x reference)
//
#include <hip/hip_runtime.h>
#include <hip/hip_bf16.h>
#include <math.h>

#define HEADS 4
#define OUTC 40
#define SLOPE 0.2f

typedef __attribute__((ext_vector_type(8))) short bf16x8;
typedef __attribute__((ext_vector_type(4))) float f32x4;

__device__ __forceinline__ short f2bf(float f) {
    unsigned u = __float_as_uint(f);
    unsigned r = (u + 0x7FFFu + ((u >> 16) & 1u)) >> 16;
    return (short)r;
}
__device__ __forceinline__ float bf2f(short s) {
    return __uint_as_float(((unsigned)(unsigned short)s) << 16);
}
__device__ __forceinline__ float bfu2f(unsigned short s) {
    return __uint_as_float(((unsigned)s) << 16);
}

typedef const __attribute__((address_space(1))) unsigned int gu32;
typedef __attribute__((address_space(3))) unsigned int lu32;
__device__ __forceinline__ void gll16(const void* src, void* lds) {
    __builtin_amdgcn_global_load_lds((gu32*)src, (lu32*)lds, 16, 0, 0);
}

// ---------------------------------------------------------------------------
// Split-bf16 MFMA GEMM: C[M,N] = A[M,K] @ B[K,N], f32 precision via hi/lo bf16
// planes and 3 MFMA products. B is pre-split TRANSPOSED planes [N][K].
// Tile: BM=128, BN=128, BK=64. 256 threads = 4 waves (2x2), 64x64 per wave.
// AF32=1: A is raw f32 [M,K], split in-register (fc1). AF32=0: A hi/lo planes.
// EPI=0: out = relu(acc+bias) -> split bf16 planes Ohi/Olo [M][N].
// EPI=1: out f32, cols<128 -> O0[M,128] (+ bf16 shadow Obf), cols>=128 -> O1.
// ---------------------------------------------------------------------------
template<int AF32, int EPI>
__global__ __launch_bounds__(256) void gemm_mfma(
    const float* __restrict__ Af,
    const short* __restrict__ Ahi, const short* __restrict__ Alo,
    const short* __restrict__ Bhi, const short* __restrict__ Blo,
    const float* __restrict__ bias,
    short* __restrict__ Ohi, short* __restrict__ Olo,
    float* __restrict__ O0, float* __restrict__ O1,
    unsigned short* __restrict__ Obf,
    int M, int N, int K)
{
    __shared__ short smem[32768];          // 64 KB
    float* AsF = (float*)smem;             // AF32: 128x64 f32 (32 KB)
    short* AsH = smem;                     // planes: 128x64 bf16 (16 KB)
    short* AsL = smem + 8192;
    short* BsH = smem + 16384;             // 128x64 bf16 (16 KB)
    short* BsL = smem + 24576;

    const int tid = threadIdx.x;
    const int wid = tid >> 6, lane = tid & 63;
    const int bm = blockIdx.y * 128, bn = blockIdx.x * 128;
    const int wm = wid >> 1, wn = wid & 1;
    const int rA = lane & 15, kb = lane >> 4;

    f32x4 acc[4][4];
    #pragma unroll
    for (int i = 0; i < 4; i++)
        #pragma unroll
        for (int j = 0; j < 4; j++)
            acc[i][j] = (f32x4){0.f, 0.f, 0.f, 0.f};

    const int KT = K >> 6;
    for (int kt = 0; kt < KT; kt++) {
        const int k0 = kt << 6;
        // ---- stage A ----
        if (AF32) {
            #pragma unroll
            for (int it = 0; it < 8; it++) {
                int g = it * 256 + tid;
                int row = g >> 4, gr = g & 15;
                int gsrc = gr ^ (row & 15);
                int grow = bm + row; if (grow > M - 1) grow = M - 1;
                gll16(Af + (size_t)grow * K + k0 + gsrc * 4,
                      AsF + (it * 256 + wid * 64) * 4);
            }
        } else {
            #pragma unroll
            for (int p = 0; p < 2; p++) {
                const short* Ap = p ? Alo : Ahi;
                short* Ds = p ? AsL : AsH;
                #pragma unroll
                for (int it = 0; it < 4; it++) {
                    int g = it * 256 + tid;
                    int row = g >> 3, gr = g & 7;
                    int gsrc = gr ^ (row & 7);
                    int grow = bm + row; if (grow > M - 1) grow = M - 1;
                    gll16(Ap + (size_t)grow * K + k0 + gsrc * 8,
                          Ds + (it * 256 + wid * 64) * 8);
                }
            }
        }
        // ---- stage B (planes, transposed [N][K]) ----
        #pragma unroll
        for (int p = 0; p < 2; p++) {
            const short* Bp = p ? Blo : Bhi;
            short* Ds = p ? BsL : BsH;
            #pragma unroll
            for (int it = 0; it < 4; it++) {
                int g = it * 256 + tid;
                int row = g >> 3, gr = g & 7;
                int gsrc = gr ^ (row & 7);
                gll16(Bp + (size_t)(bn + row) * K + k0 + gsrc * 8,
                      Ds + (it * 256 + wid * 64) * 8);
            }
        }
        __syncthreads();
        // ---- compute ----
        #pragma unroll
        for (int kc = 0; kc < 2; kc++) {
            bf16x8 ah[4], al[4], bh[4], bl[4];
            if (AF32) {
                #pragma unroll
                for (int mi = 0; mi < 4; mi++) {
                    int r = wm * 64 + mi * 16 + rA;
                    int g0 = kc * 8 + kb * 2;
                    float4 f0 = *(const float4*)(AsF + r * 64 + ((g0 ^ (r & 15)) * 4));
                    float4 f1 = *(const float4*)(AsF + r * 64 + (((g0 + 1) ^ (r & 15)) * 4));
                    float fv[8] = {f0.x, f0.y, f0.z, f0.w, f1.x, f1.y, f1.z, f1.w};
                    #pragma unroll
                    for (int j = 0; j < 8; j++) {
                        short h = f2bf(fv[j]);
                        ah[mi][j] = h;
                        al[mi][j] = f2bf(fv[j] - bf2f(h));
                    }
                }
            } else {
                #pragma unroll
                for (int mi = 0; mi < 4; mi++) {
                    int r = wm * 64 + mi * 16 + rA;
                    int off = r * 64 + (((kc * 4 + kb) ^ (r & 7)) * 8);
                    ah[mi] = *(const bf16x8*)(AsH + off);
                    al[mi] = *(const bf16x8*)(AsL + off);
                }
            }
            #pragma unroll
            for (int ni = 0; ni < 4; ni++) {
                int r = wn * 64 + ni * 16 + rA;
                int off = r * 64 + (((kc * 4 + kb) ^ (r & 7)) * 8);
                bh[ni] = *(const bf16x8*)(BsH + off);
                bl[ni] = *(const bf16x8*)(BsL + off);
            }
            #pragma unroll
            for (int mi = 0; mi < 4; mi++)
                #pragma unroll
                for (int ni = 0; ni < 4; ni++) {
                    acc[mi][ni] = __builtin_amdgcn_mfma_f32_16x16x32_bf16(ah[mi], bh[ni], acc[mi][ni], 0, 0, 0);
                    acc[mi][ni] = __builtin_amdgcn_mfma_f32_16x16x32_bf16(ah[mi], bl[ni], acc[mi][ni], 0, 0, 0);
                    acc[mi][ni] = __builtin_amdgcn_mfma_f32_16x16x32_bf16(al[mi], bh[ni], acc[mi][ni], 0, 0, 0);
                }
        }
        __syncthreads();
    }

    // ---- epilogue (C/D map: col=lane&15, row=(lane>>4)*4+j) ----
    #pragma unroll
    for (int ni = 0; ni < 4; ni++) {
        int col = bn + wn * 64 + ni * 16 + rA;
        float bv = (EPI == 0) ? bias[col] : 0.f;
        #pragma unroll
        for (int mi = 0; mi < 4; mi++) {
            #pragma unroll
            for (int j = 0; j < 4; j++) {
                int row = bm + wm * 64 + mi * 16 + kb * 4 + j;
                if (row < M) {
                    float v = acc[mi][ni][j];
                    if (EPI == 0) {
                        v = fmaxf(v + bv, 0.f);
                        short h = f2bf(v);
                        Ohi[(size_t)row * N + col] = h;
                        Olo[(size_t)row * N + col] = f2bf(v - bf2f(h));
                    } else {
                        if (col < 128) {
                            O0[(size_t)row * 128 + col] = v;
                            Obf[(size_t)row * 128 + col] = (unsigned short)f2bf(v);
                        } else {
                            O1[(size_t)row * 128 + (col - 128)] = v;
                        }
                    }
                }
            }
        }
    }
}

// ---------------------------------------------------------------------------
// f32 vector GEMM (used for the small N=80 merged gat2/res2 matmul).
// Also writes a bf16 shadow of cols<40 (the gat2 h2 part) for the gather.
// ---------------------------------------------------------------------------
__global__ __launch_bounds__(256) void gemm_bias(const float* __restrict__ A,
                                                 const float* __restrict__ B,
                                                 const float* __restrict__ bias,
                                                 float* __restrict__ C,
                                                 unsigned short* __restrict__ Cbf,
                                                 int M, int N, int K) {
    __shared__ float As[16][65];
    __shared__ float Bs[16][64];
    int tid = threadIdx.x;
    int tx = tid & 15, ty = tid >> 4;
    int bm = blockIdx.y * 64, bn = blockIdx.x * 64;
    int arow = tid >> 2, acol = (tid & 3) << 2;
    int brow = tid >> 4, bcol = (tid & 15) << 2;
    bool fullM = (bm + 64 <= M);
    bool fullN = (bn + 64 <= N);
    float acc[4][4] = {{0.f}};

    for (int k0 = 0; k0 < K; k0 += 16) {
        if (fullM) {
            const float4 av = *(const float4*)(A + (size_t)(bm + arow) * K + (k0 + acol));
            As[acol + 0][arow] = av.x; As[acol + 1][arow] = av.y;
            As[acol + 2][arow] = av.z; As[acol + 3][arow] = av.w;
        } else {
            int r = bm + arow;
            #pragma unroll
            for (int i = 0; i < 4; i++)
                As[acol + i][arow] = (r < M) ? A[(size_t)r * K + k0 + acol + i] : 0.f;
        }
        if (fullN) {
            *(float4*)(&Bs[brow][bcol]) = *(const float4*)(B + (size_t)(k0 + brow) * N + (bn + bcol));
        } else {
            #pragma unroll
            for (int i = 0; i < 4; i++) {
                int c = bn + bcol + i;
                Bs[brow][bcol + i] = (c < N) ? B[(size_t)(k0 + brow) * N + c] : 0.f;
            }
        }
        __syncthreads();
        #pragma unroll
        for (int kk = 0; kk < 16; kk++) {
            float a[4], b[4];
            #pragma unroll
            for (int i = 0; i < 4; i++) a[i] = As[kk][ty * 4 + i];
            #pragma unroll
            for (int j = 0; j < 4; j++) b[j] = Bs[kk][tx * 4 + j];
            #pragma unroll
            for (int i = 0; i < 4; i++)
                #pragma unroll
                for (int j = 0; j < 4; j++) acc[i][j] += a[i] * b[j];
        }
        __syncthreads();
    }

    #pragma unroll
    for (int i = 0; i < 4; i++) {
        int r = bm + ty * 4 + i;
        if (r < M) {
            #pragma unroll
            for (int j = 0; j < 4; j++) {
                int c = bn + tx * 4 + j;
                if (c < N) {
                    float v = acc[i][j] + (bias ? bias[c] : 0.f);
                    C[(size_t)r * N + c] = v;
                    if (Cbf && c < OUTC)
                        Cbf[(size_t)r * OUTC + c] = (unsigned short)f2bf(v);
                }
            }
        }
    }
}

// ---------------------------------------------------------------------------
// Weight conversion kernels
// ---------------------------------------------------------------------------
__global__ void wt_split(const float* __restrict__ Wm, int K, int Nn,
                         short* __restrict__ hi, short* __restrict__ lo) {
    int idx = blockIdx.x * blockDim.x + threadIdx.x;
    if (idx >= K * Nn) return;
    int n = idx / K, k = idx - n * K;
    float v = Wm[(size_t)k * Nn + n];
    short h = f2bf(v);
    hi[idx] = h; lo[idx] = f2bf(v - bf2f(h));
}

__global__ void wt_split2(const float* __restrict__ Wg, const float* __restrict__ Wr,
                          int K, int Nh, short* __restrict__ hi, short* __restrict__ lo) {
    int idx = blockIdx.x * blockDim.x + threadIdx.x;
    if (idx >= K * 2 * Nh) return;
    int n = idx / K, k = idx - n * K;
    float v = (n < Nh) ? Wg[(size_t)k * Nh + n] : Wr[(size_t)k * Nh + (n - Nh)];
    short h = f2bf(v);
    hi[idx] = h; lo[idx] = f2bf(v - bf2f(h));
}

__global__ void build_wc2(const float* __restrict__ g2w, const float* __restrict__ r2w,
                          const float* __restrict__ r2b,
                          float* __restrict__ wc2, float* __restrict__ cb2) {
    int idx = blockIdx.x * blockDim.x + threadIdx.x;
    if (idx < 128 * 80) {
        int k = idx / 80, n = idx - k * 80;
        wc2[idx] = (n < 40) ? g2w[k * 40 + n] : r2w[k * 40 + (n - 40)];
    }
    if (idx < 80) cb2[idx] = (idx < 40) ? 0.f : r2b[idx - 40];
}

// ---------------------------------------------------------------------------
// CSR build
// ---------------------------------------------------------------------------
__global__ void count_deg(const int* __restrict__ dstA, int E, int* __restrict__ deg) {
    int e = blockIdx.x * blockDim.x + threadIdx.x;
    if (e < E) atomicAdd(&deg[dstA[e]], 1);
}

__global__ void scan_part(const int* __restrict__ deg, int N, int* __restrict__ part) {
    __shared__ int s[256];
    int b = blockIdx.x, t = threadIdx.x;
    int i0 = b * 1024 + t * 4;
    int sum = 0;
    #pragma unroll
    for (int j = 0; j < 4; j++) { int i = i0 + j; if (i < N) sum += deg[i] + 1; }
    s[t] = sum; __syncthreads();
    for (int o = 128; o; o >>= 1) { if (t < o) s[t] += s[t + o]; __syncthreads(); }
    if (t == 0) part[b] = s[0];
}

__global__ void scan_base(int* __restrict__ part, int nb, int* __restrict__ offs) {
    int t = threadIdx.x;
    int v = (t < nb) ? part[t] : 0;
    int v0 = v;
    for (int o = 1; o < 64; o <<= 1) {
        int u = __shfl_up(v, o, 64);
        if (t >= o) v += u;
    }
    if (t < nb) part[t] = v - v0;   // exclusive
    if (t == 0) offs[0] = 0;
}

__global__ void scan_final(const int* __restrict__ deg, int N, const int* __restrict__ part,
                           int* __restrict__ offs, int* __restrict__ cur) {
    __shared__ int s[256];
    int b = blockIdx.x, t = threadIdx.x;
    int i0 = b * 1024 + t * 4;
    int v[4]; int sum = 0;
    #pragma unroll
    for (int j = 0; j < 4; j++) { int i = i0 + j; v[j] = (i < N) ? deg[i] + 1 : 0; sum += v[j]; }
    s[t] = sum; __syncthreads();
    for (int o = 1; o < 256; o <<= 1) {
        int add = (t >= o) ? s[t - o] : 0;
        __syncthreads();
        s[t] += add;
        __syncthreads();
    }
    int excl = s[t] - sum + part[b];
    #pragma unroll
    for (int j = 0; j < 4; j++) {
        int i = i0 + j;
        if (i < N) { cur[i] = excl; offs[i + 1] = excl + v[j]; excl += v[j]; }
    }
}

__global__ void scatter_k(const int* __restrict__ srcA, const int* __restrict__ dstA,
                          int E, int* __restrict__ cur, int* __restrict__ csr) {
    int e = blockIdx.x * blockDim.x + threadIdx.x;
    if (e < E) {
        int p = atomicAdd(&cur[dstA[e]], 1);
        csr[p] = srcA[e];
    }
}

__global__ void selfloop_k(const int* __restrict__ offs, int* __restrict__ csr, int N) {
    int n = blockIdx.x * blockDim.x + threadIdx.x;
    if (n < N) csr[offs[n + 1] - 1] = n;
}

// ---------------------------------------------------------------------------
// Attention score vectors
// ---------------------------------------------------------------------------
__global__ void att1(const float* __restrict__ h1, const float* __restrict__ atts,
                     const float* __restrict__ attd, float* __restrict__ as1,
                     float* __restrict__ ad1, int N) {
    int idx = blockIdx.x * blockDim.x + threadIdx.x;
    if (idx >= N * HEADS) return;
    int n = idx >> 2, h = idx & 3;
    const float* row = h1 + (size_t)n * 128 + h * 32;
    float ss = 0.f, dd = 0.f;
    #pragma unroll
    for (int c = 0; c < 32; c++) {
        float v = row[c];
        ss += v * atts[h * 32 + c];
        dd += v * attd[h * 32 + c];
    }
    as1[idx] = ss; ad1[idx] = dd;
}

__global__ void att2(const float* __restrict__ h2r2, const float* __restrict__ atts,
                     const float* __restrict__ attd, float* __restrict__ as2,
                     float* __restrict__ ad2, int N) {
    int n = blockIdx.x * blockDim.x + threadIdx.x;
    if (n >= N) return;
    const float* row = h2r2 + (size_t)n * 80;
    float ss = 0.f, dd = 0.f;
    #pragma unroll
    for (int c = 0; c < OUTC; c++) {
        float v = row[c];
        ss += v * atts[c];
        dd += v * attd[c];
    }
    as2[n] = ss; ad2[n] = dd;
}

// ---------------------------------------------------------------------------
// GAT1 aggregation: one WAVE per node (4 nodes / 256-thread block).
// Thread t (0..63) owns channels {2t, 2t+1}; head h = t>>4.
// Pass 1: per-head max (16-lane strided + butterfly).
// Pass 2 (fused): serial over edges, w=exp(v-mx); den += w (identical across
// head group, no reduce); acc += w * bf16(h1[src]). Epilogue: /den + biases
// + r1, relu -> f32 hbuf.
// ---------------------------------------------------------------------------
__global__ __launch_bounds__(256) void gat1_agg(const unsigned short* __restrict__ h1b,
                                                const float* __restrict__ r1,
                                                const float* __restrict__ as1,
                                                const float* __restrict__ ad1,
                                                const int* __restrict__ offs,
                                                const int* __restrict__ csr,
                                                const float* __restrict__ gb,
                                                const float* __restrict__ rb,
                                                float* __restrict__ outh, int N) {
    int n = blockIdx.x * 4 + (threadIdx.x >> 6);
    if (n >= N) return;
    int t = threadIdx.x & 63;
    int h = t >> 4;
    int l16 = t & 15;
    int beg = offs[n], d = offs[n + 1] - beg;
    float adst = ad1[n * HEADS + h];

    float mx = -INFINITY;
    for (int j = l16; j < d; j += 16) {
        int s = csr[beg + j];
        float v = as1[s * HEADS + h] + adst;
        v = v >= 0.f ? v : SLOPE * v;
        mx = fmaxf(mx, v);
    }
    #pragma unroll
    for (int o = 8; o; o >>= 1) mx = fmaxf(mx, __shfl_xor(mx, o, 16));

    float den = 0.f;
    float a0 = 0.f, a1 = 0.f;
    for (int j = 0; j < d; j++) {
        int s = csr[beg + j];
        float v = as1[s * HEADS + h] + adst;
        v = v >= 0.f ? v : SLOPE * v;
        float w = __expf(v - mx);
        den += w;
        ushort2 hv = *(const ushort2*)(h1b + (size_t)s * 128 + 2 * t);
        a0 += w * bfu2f(hv.x);
        a1 += w * bfu2f(hv.y);
    }
    den = fmaxf(den, 1e-16f);
    float inv = 1.f / den;
    float2 rv = *(const float2*)(r1 + (size_t)n * 128 + 2 * t);
    float o0 = fmaxf(a0 * inv + gb[2 * t]     + rb[2 * t]     + rv.x, 0.f);
    float o1 = fmaxf(a1 * inv + gb[2 * t + 1] + rb[2 * t + 1] + rv.y, 0.f);
    float2 ov = {o0, o1};
    *(float2*)(outh + (size_t)n * 128 + 2 * t) = ov;
}

// ---------------------------------------------------------------------------
// GAT2 aggregation: one WAVE per node (4 nodes / 256-thread block), 1 head.
// Max via 64-lane strided pass; fused den+acc serial pass (threads t<40 own
// one channel each, bf16 gather). Epilogue: /den + gat2_b + r2 -> out.
// ---------------------------------------------------------------------------
__global__ __launch_bounds__(256) void gat2_agg(const unsigned short* __restrict__ h2b,
                                                const float* __restrict__ h2r2,
                                                const float* __restrict__ as2,
                                                const float* __restrict__ ad2,
                                                const int* __restrict__ offs,
                                                const int* __restrict__ csr,
                                                const float* __restrict__ gb,
                                                float* __restrict__ out, int N) {
    int n = blockIdx.x * 4 + (threadIdx.x >> 6);
    if (n >= N) return;
    int t = threadIdx.x & 63;
    int beg = offs[n], d = offs[n + 1] - beg;
    float adst = ad2[n];

    float mx = -INFINITY;
    for (int j = t; j < d; j += 64) {
        int s = csr[beg + j];
        float v = as2[s] + adst;
        v = v >= 0.f ? v : SLOPE * v;
        mx = fmaxf(mx, v);
    }
    #pragma unroll
    for (int o = 32; o; o >>= 1) mx = fmaxf(mx, __shfl_xor(mx, o, 64));

    float den = 0.f, acc = 0.f;
    for (int j = 0; j < d; j++) {
        int s = csr[beg + j];
        float v = as2[s] + adst;
        v = v >= 0.f ? v : SLOPE * v;
        float w = __expf(v - mx);
        den += w;
        if (t < OUTC) acc += w * bfu2f(h2b[(size_t)s * OUTC + t]);
    }
    den = fmaxf(den, 1e-16f);
    if (t < OUTC)
        out[(size_t)n * OUTC + t] = acc / den + gb[t] + h2r2[(size_t)n * 80 + 40 + t];
}

// ---------------------------------------------------------------------------
// Launcher
// ---------------------------------------------------------------------------
extern "C" void kernel_launch(void* const* d_in, const int* in_sizes, int n_in,
                              void* d_out, int out_size, void* d_ws, size_t ws_size,
                              hipStream_t stream) {
    const float* x      = (const float*)d_in[0];
    const int*   ei     = (const int*)d_in[1];
    const float* ae_w1  = (const float*)d_in[2];
    const float* ae_b1  = (const float*)d_in[3];
    const float* ae_w2  = (const float*)d_in[4];
    const float* ae_b2  = (const float*)d_in[5];
    const float* gat1_w = (const float*)d_in[6];
    const float* g1as   = (const float*)d_in[7];
    const float* g1ad   = (const float*)d_in[8];
    const float* g1b    = (const float*)d_in[9];
    const float* gat2_w = (const float*)d_in[10];
    const float* g2as   = (const float*)d_in[11];
    const float* g2ad   = (const float*)d_in[12];
    const float* g2b    = (const float*)d_in[13];
    const float* res1_w = (const float*)d_in[14];
    const float* res1_b = (const float*)d_in[15];
    const float* res2_w = (const float*)d_in[16];
    const float* res2_b = (const float*)d_in[17];
    float* out = (float*)d_out;

    const int Nn = in_sizes[0] / 512;       // 50000 nodes
    const int E  = in_sizes[1] / 2;         // 800000 edges

    const int* srcA = ei;
    const int* dstA = ei + E;

    // ---- workspace layout (bytes) ----
    char* W = (char*)d_ws;
    size_t off = 0;
    auto alloc = [&](size_t bytes) { char* p = W + off; off += (bytes + 255) & ~(size_t)255; return p; };

    const size_t regA = (size_t)Nn * 256 * 2;   // 25.6 MB (one plane) == Nn*128*4
    char* pA = alloc(2 * regA);                 // y1 planes -> later h1 | r1
    short* y1hi = (short*)pA;
    short* y1lo = (short*)(pA + regA);
    float* h1   = (float*)pA;
    float* r1   = (float*)(pA + regA);

    char* pB = alloc(2 * regA);                 // xe planes -> later hbuf | h2r2
    short* xehi = (short*)pB;
    short* xelo = (short*)(pB + regA);
    float* hbuf = (float*)pB;
    float* h2r2 = (float*)(pB + regA);          // [Nn,80]

    unsigned short* h1bf = (unsigned short*)alloc((size_t)Nn * 128 * 2);  // 12.8 MB
    unsigned short* h2bf = (unsigned short*)alloc((size_t)Nn * OUTC * 2); // 4 MB

    short* w1Thi = (short*)alloc(256 * 512 * 2);
    short* w1Tlo = (short*)alloc(256 * 512 * 2);
    short* w2Thi = (short*)alloc(256 * 256 * 2);
    short* w2Tlo = (short*)alloc(256 * 256 * 2);
    short* wc1hi = (short*)alloc(256 * 256 * 2);
    short* wc1lo = (short*)alloc(256 * 256 * 2);
    float* wc2   = (float*)alloc(128 * 80 * 4);
    float* cb2   = (float*)alloc(128 * 4);
    float* as1   = (float*)alloc((size_t)Nn * HEADS * 4);
    float* ad1   = (float*)alloc((size_t)Nn * HEADS * 4);
    float* as2   = (float*)alloc((size_t)Nn * 4);
    float* ad2   = (float*)alloc((size_t)Nn * 4);
    int* deg  = (int*)alloc((size_t)Nn * 4);
    int* offs = (int*)alloc((size_t)(Nn + 1) * 4);
    int* cur  = (int*)alloc((size_t)Nn * 4);
    int* part = (int*)alloc(256 * 4);
    int* csr  = (int*)alloc((size_t)(E + Nn) * 4);

    // ---- weight prep ----
    wt_split<<<(512 * 256 + 255) / 256, 256, 0, stream>>>(ae_w1, 512, 256, w1Thi, w1Tlo);
    wt_split<<<(256 * 256 + 255) / 256, 256, 0, stream>>>(ae_w2, 256, 256, w2Thi, w2Tlo);
    wt_split2<<<(256 * 256 + 255) / 256, 256, 0, stream>>>(gat1_w, res1_w, 256, 128, wc1hi, wc1lo);
    build_wc2<<<(128 * 80 + 255) / 256, 256, 0, stream>>>(gat2_w, res2_w, res2_b, wc2, cb2);

    // ---- CSR build ----
    hipMemsetAsync(deg, 0, (size_t)Nn * sizeof(int), stream);
    count_deg<<<(E + 255) / 256, 256, 0, stream>>>(dstA, E, deg);
    int nb = (Nn + 1023) / 1024;
    scan_part<<<nb, 256, 0, stream>>>(deg, Nn, part);
    scan_base<<<1, 64, 0, stream>>>(part, nb, offs);
    scan_final<<<nb, 256, 0, stream>>>(deg, Nn, part, offs, cur);
    scatter_k<<<(E + 255) / 256, 256, 0, stream>>>(srcA, dstA, E, cur, csr);
    selfloop_k<<<(Nn + 255) / 256, 256, 0, stream>>>(offs, csr, Nn);

    const int gy = (Nn + 127) / 128;   // 391

    // ---- fc1: relu(x @ ae_w1 + b1) -> y1 planes ----
    gemm_mfma<1, 0><<<dim3(2, gy), 256, 0, stream>>>(
        x, nullptr, nullptr, w1Thi, w1Tlo, ae_b1,
        y1hi, y1lo, nullptr, nullptr, nullptr, Nn, 256, 512);

    // ---- fc2: relu(y1 @ ae_w2 + b2) -> xe planes ----
    gemm_mfma<0, 0><<<dim3(2, gy), 256, 0, stream>>>(
        nullptr, y1hi, y1lo, w2Thi, w2Tlo, ae_b2,
        xehi, xelo, nullptr, nullptr, nullptr, Nn, 256, 256);

    // ---- gatres1: xe @ [gat1_w | res1_w] -> h1 [Nn,128] (+bf16 shadow), r1 ----
    gemm_mfma<0, 1><<<dim3(2, gy), 256, 0, stream>>>(
        nullptr, xehi, xelo, wc1hi, wc1lo, nullptr,
        nullptr, nullptr, h1, r1, h1bf, Nn, 256, 256);

    att1<<<(Nn * HEADS + 255) / 256, 256, 0, stream>>>(h1, g1as, g1ad, as1, ad1, Nn);
    gat1_agg<<<(Nn + 3) / 4, 256, 0, stream>>>(h1bf, r1, as1, ad1, offs, csr, g1b, res1_b, hbuf, Nn);

    // ---- gatres2 (f32): hbuf @ [gat2_w | res2_w] + [0|res2_b] -> h2r2 [Nn,80] ----
    gemm_bias<<<dim3(2, (Nn + 63) / 64), 256, 0, stream>>>(hbuf, wc2, cb2, h2r2, h2bf, Nn, 80, 128);

    att2<<<(Nn + 255) / 256, 256, 0, stream>>>(h2r2, g2as, g2ad, as2, ad2, Nn);
    gat2_agg<<<(Nn + 3) / 4, 256, 0, stream>>>(h2bf, h2r2, as2, ad2, offs, csr, g2b, out, Nn);
}

// Round 4
// 496.304 us; speedup vs baseline: 1.0826x; 1.0826x over previous
//
#include <hip/hip_runtime.h>
#include <hip/hip_bf16.h>
#include <math.h>

#define HEADS 4
#define OUTC 40
#define SLOPE 0.2f

typedef __attribute__((ext_vector_type(8))) short bf16x8;
typedef __attribute__((ext_vector_type(4))) float f32x4;

__device__ __forceinline__ short f2bf(float f) {
    unsigned u = __float_as_uint(f);
    unsigned r = (u + 0x7FFFu + ((u >> 16) & 1u)) >> 16;
    return (short)r;
}
__device__ __forceinline__ float bf2f(short s) {
    return __uint_as_float(((unsigned)(unsigned short)s) << 16);
}
__device__ __forceinline__ float bfu2f(unsigned short s) {
    return __uint_as_float(((unsigned)s) << 16);
}

typedef const __attribute__((address_space(1))) unsigned int gu32;
typedef __attribute__((address_space(3))) unsigned int lu32;
__device__ __forceinline__ void gll16(const void* src, void* lds) {
    __builtin_amdgcn_global_load_lds((gu32*)src, (lu32*)lds, 16, 0, 0);
}

// ---------------------------------------------------------------------------
// x -> bf16 conversion (pure BW pass)
// ---------------------------------------------------------------------------
__global__ void x2bf(const float* __restrict__ x, unsigned int* __restrict__ xb,
                     long total) {
    long i = ((long)blockIdx.x * blockDim.x + threadIdx.x) * 8;
    if (i >= total) return;
    float4 a = *(const float4*)(x + i);
    float4 b = *(const float4*)(x + i + 4);
    uint4 o;
    o.x = (unsigned short)f2bf(a.x) | ((unsigned)(unsigned short)f2bf(a.y) << 16);
    o.y = (unsigned short)f2bf(a.z) | ((unsigned)(unsigned short)f2bf(a.w) << 16);
    o.z = (unsigned short)f2bf(b.x) | ((unsigned)(unsigned short)f2bf(b.y) << 16);
    o.w = (unsigned short)f2bf(b.z) | ((unsigned)(unsigned short)f2bf(b.w) << 16);
    *(uint4*)(xb + i / 2) = o;
}

// ---------------------------------------------------------------------------
// bf16-A MFMA GEMM: C[M,N] = A[M,K] @ B[K,N]. A is a single bf16 plane;
// B is pre-split TRANSPOSED hi/lo planes [N][K] (2 MFMAs: a*bh + a*bl).
// Tile: BM=128, BN=128, BK=64. 256 threads = 4 waves (2x2), 64x64 per wave.
// LDS = 48 KB -> 3 blocks/CU.
// EPI=0: out = relu(acc+bias) -> bf16 [M][N].
// EPI=1: cols<128 -> bf16 Obf[M,128]; cols>=128 -> f32 Of[M,128]. No bias.
// ---------------------------------------------------------------------------
template<int EPI>
__global__ __launch_bounds__(256) void gemm2(
    const short* __restrict__ A,
    const short* __restrict__ Bhi, const short* __restrict__ Blo,
    const float* __restrict__ bias,
    unsigned short* __restrict__ Obf, float* __restrict__ Of,
    int M, int N, int K)
{
    __shared__ short smem[24576];          // 48 KB
    short* As  = smem;                     // 128x64 bf16 (16 KB)
    short* BsH = smem + 8192;
    short* BsL = smem + 16384;

    const int tid = threadIdx.x;
    const int wid = tid >> 6, lane = tid & 63;
    const int bm = blockIdx.y * 128, bn = blockIdx.x * 128;
    const int wm = wid >> 1, wn = wid & 1;
    const int rA = lane & 15, kb = lane >> 4;

    f32x4 acc[4][4];
    #pragma unroll
    for (int i = 0; i < 4; i++)
        #pragma unroll
        for (int j = 0; j < 4; j++)
            acc[i][j] = (f32x4){0.f, 0.f, 0.f, 0.f};

    const int KT = K >> 6;
    for (int kt = 0; kt < KT; kt++) {
        const int k0 = kt << 6;
        // ---- stage A (single plane) ----
        #pragma unroll
        for (int it = 0; it < 4; it++) {
            int g = it * 256 + tid;
            int row = g >> 3, gr = g & 7;
            int gsrc = gr ^ (row & 7);
            int grow = bm + row; if (grow > M - 1) grow = M - 1;
            gll16(A + (size_t)grow * K + k0 + gsrc * 8,
                  As + (it * 256 + wid * 64) * 8);
        }
        // ---- stage B hi/lo ----
        #pragma unroll
        for (int p = 0; p < 2; p++) {
            const short* Bp = p ? Blo : Bhi;
            short* Ds = p ? BsL : BsH;
            #pragma unroll
            for (int it = 0; it < 4; it++) {
                int g = it * 256 + tid;
                int row = g >> 3, gr = g & 7;
                int gsrc = gr ^ (row & 7);
                gll16(Bp + (size_t)(bn + row) * K + k0 + gsrc * 8,
                      Ds + (it * 256 + wid * 64) * 8);
            }
        }
        __syncthreads();
        // ---- compute ----
        #pragma unroll
        for (int kc = 0; kc < 2; kc++) {
            bf16x8 a[4], bh[4], bl[4];
            #pragma unroll
            for (int mi = 0; mi < 4; mi++) {
                int r = wm * 64 + mi * 16 + rA;
                int off = r * 64 + (((kc * 4 + kb) ^ (r & 7)) * 8);
                a[mi] = *(const bf16x8*)(As + off);
            }
            #pragma unroll
            for (int ni = 0; ni < 4; ni++) {
                int r = wn * 64 + ni * 16 + rA;
                int off = r * 64 + (((kc * 4 + kb) ^ (r & 7)) * 8);
                bh[ni] = *(const bf16x8*)(BsH + off);
                bl[ni] = *(const bf16x8*)(BsL + off);
            }
            #pragma unroll
            for (int mi = 0; mi < 4; mi++)
                #pragma unroll
                for (int ni = 0; ni < 4; ni++) {
                    acc[mi][ni] = __builtin_amdgcn_mfma_f32_16x16x32_bf16(a[mi], bh[ni], acc[mi][ni], 0, 0, 0);
                    acc[mi][ni] = __builtin_amdgcn_mfma_f32_16x16x32_bf16(a[mi], bl[ni], acc[mi][ni], 0, 0, 0);
                }
        }
        __syncthreads();
    }

    // ---- epilogue (C/D map: col=lane&15, row=(lane>>4)*4+j) ----
    #pragma unroll
    for (int ni = 0; ni < 4; ni++) {
        int col = bn + wn * 64 + ni * 16 + rA;
        float bv = (EPI == 0) ? bias[col] : 0.f;
        #pragma unroll
        for (int mi = 0; mi < 4; mi++) {
            #pragma unroll
            for (int j = 0; j < 4; j++) {
                int row = bm + wm * 64 + mi * 16 + kb * 4 + j;
                if (row < M) {
                    float v = acc[mi][ni][j];
                    if (EPI == 0) {
                        v = fmaxf(v + bv, 0.f);
                        Obf[(size_t)row * N + col] = (unsigned short)f2bf(v);
                    } else {
                        if (col < 128) Obf[(size_t)row * 128 + col] = (unsigned short)f2bf(v);
                        else           Of[(size_t)row * 128 + (col - 128)] = v;
                    }
                }
            }
        }
    }
}

// ---------------------------------------------------------------------------
// f32 vector GEMM (small N=80 merged gat2/res2 matmul) + bf16 shadow of
// cols<40 for the gather.
// ---------------------------------------------------------------------------
__global__ __launch_bounds__(256) void gemm_bias(const float* __restrict__ A,
                                                 const float* __restrict__ B,
                                                 const float* __restrict__ bias,
                                                 float* __restrict__ C,
                                                 unsigned short* __restrict__ Cbf,
                                                 int M, int N, int K) {
    __shared__ float As[16][65];
    __shared__ float Bs[16][64];
    int tid = threadIdx.x;
    int tx = tid & 15, ty = tid >> 4;
    int bm = blockIdx.y * 64, bn = blockIdx.x * 64;
    int arow = tid >> 2, acol = (tid & 3) << 2;
    int brow = tid >> 4, bcol = (tid & 15) << 2;
    bool fullM = (bm + 64 <= M);
    bool fullN = (bn + 64 <= N);
    float acc[4][4] = {{0.f}};

    for (int k0 = 0; k0 < K; k0 += 16) {
        if (fullM) {
            const float4 av = *(const float4*)(A + (size_t)(bm + arow) * K + (k0 + acol));
            As[acol + 0][arow] = av.x; As[acol + 1][arow] = av.y;
            As[acol + 2][arow] = av.z; As[acol + 3][arow] = av.w;
        } else {
            int r = bm + arow;
            #pragma unroll
            for (int i = 0; i < 4; i++)
                As[acol + i][arow] = (r < M) ? A[(size_t)r * K + k0 + acol + i] : 0.f;
        }
        if (fullN) {
            *(float4*)(&Bs[brow][bcol]) = *(const float4*)(B + (size_t)(k0 + brow) * N + (bn + bcol));
        } else {
            #pragma unroll
            for (int i = 0; i < 4; i++) {
                int c = bn + bcol + i;
                Bs[brow][bcol + i] = (c < N) ? B[(size_t)(k0 + brow) * N + c] : 0.f;
            }
        }
        __syncthreads();
        #pragma unroll
        for (int kk = 0; kk < 16; kk++) {
            float a[4], b[4];
            #pragma unroll
            for (int i = 0; i < 4; i++) a[i] = As[kk][ty * 4 + i];
            #pragma unroll
            for (int j = 0; j < 4; j++) b[j] = Bs[kk][tx * 4 + j];
            #pragma unroll
            for (int i = 0; i < 4; i++)
                #pragma unroll
                for (int j = 0; j < 4; j++) acc[i][j] += a[i] * b[j];
        }
        __syncthreads();
    }

    #pragma unroll
    for (int i = 0; i < 4; i++) {
        int r = bm + ty * 4 + i;
        if (r < M) {
            #pragma unroll
            for (int j = 0; j < 4; j++) {
                int c = bn + tx * 4 + j;
                if (c < N) {
                    float v = acc[i][j] + (bias ? bias[c] : 0.f);
                    C[(size_t)r * N + c] = v;
                    if (Cbf && c < OUTC)
                        Cbf[(size_t)r * OUTC + c] = (unsigned short)f2bf(v);
                }
            }
        }
    }
}

// ---------------------------------------------------------------------------
// Weight conversion kernels
// ---------------------------------------------------------------------------
__global__ void wt_split(const float* __restrict__ Wm, int K, int Nn,
                         short* __restrict__ hi, short* __restrict__ lo) {
    int idx = blockIdx.x * blockDim.x + threadIdx.x;
    if (idx >= K * Nn) return;
    int n = idx / K, k = idx - n * K;
    float v = Wm[(size_t)k * Nn + n];
    short h = f2bf(v);
    hi[idx] = h; lo[idx] = f2bf(v - bf2f(h));
}

__global__ void wt_split2(const float* __restrict__ Wg, const float* __restrict__ Wr,
                          int K, int Nh, short* __restrict__ hi, short* __restrict__ lo) {
    int idx = blockIdx.x * blockDim.x + threadIdx.x;
    if (idx >= K * 2 * Nh) return;
    int n = idx / K, k = idx - n * K;
    float v = (n < Nh) ? Wg[(size_t)k * Nh + n] : Wr[(size_t)k * Nh + (n - Nh)];
    short h = f2bf(v);
    hi[idx] = h; lo[idx] = f2bf(v - bf2f(h));
}

__global__ void build_wc2(const float* __restrict__ g2w, const float* __restrict__ r2w,
                          const float* __restrict__ r2b,
                          float* __restrict__ wc2, float* __restrict__ cb2) {
    int idx = blockIdx.x * blockDim.x + threadIdx.x;
    if (idx < 128 * 80) {
        int k = idx / 80, n = idx - k * 80;
        wc2[idx] = (n < 40) ? g2w[k * 40 + n] : r2w[k * 40 + (n - 40)];
    }
    if (idx < 80) cb2[idx] = (idx < 40) ? 0.f : r2b[idx - 40];
}

// ---------------------------------------------------------------------------
// CSR build
// ---------------------------------------------------------------------------
__global__ void count_deg(const int* __restrict__ dstA, int E, int* __restrict__ deg) {
    int e = blockIdx.x * blockDim.x + threadIdx.x;
    if (e < E) atomicAdd(&deg[dstA[e]], 1);
}

__global__ void scan_part(const int* __restrict__ deg, int N, int* __restrict__ part) {
    __shared__ int s[256];
    int b = blockIdx.x, t = threadIdx.x;
    int i0 = b * 1024 + t * 4;
    int sum = 0;
    #pragma unroll
    for (int j = 0; j < 4; j++) { int i = i0 + j; if (i < N) sum += deg[i] + 1; }
    s[t] = sum; __syncthreads();
    for (int o = 128; o; o >>= 1) { if (t < o) s[t] += s[t + o]; __syncthreads(); }
    if (t == 0) part[b] = s[0];
}

__global__ void scan_base(int* __restrict__ part, int nb, int* __restrict__ offs) {
    int t = threadIdx.x;
    int v = (t < nb) ? part[t] : 0;
    int v0 = v;
    for (int o = 1; o < 64; o <<= 1) {
        int u = __shfl_up(v, o, 64);
        if (t >= o) v += u;
    }
    if (t < nb) part[t] = v - v0;   // exclusive
    if (t == 0) offs[0] = 0;
}

__global__ void scan_final(const int* __restrict__ deg, int N, const int* __restrict__ part,
                           int* __restrict__ offs, int* __restrict__ cur) {
    __shared__ int s[256];
    int b = blockIdx.x, t = threadIdx.x;
    int i0 = b * 1024 + t * 4;
    int v[4]; int sum = 0;
    #pragma unroll
    for (int j = 0; j < 4; j++) { int i = i0 + j; v[j] = (i < N) ? deg[i] + 1 : 0; sum += v[j]; }
    s[t] = sum; __syncthreads();
    for (int o = 1; o < 256; o <<= 1) {
        int add = (t >= o) ? s[t - o] : 0;
        __syncthreads();
        s[t] += add;
        __syncthreads();
    }
    int excl = s[t] - sum + part[b];
    #pragma unroll
    for (int j = 0; j < 4; j++) {
        int i = i0 + j;
        if (i < N) { cur[i] = excl; offs[i + 1] = excl + v[j]; excl += v[j]; }
    }
}

__global__ void scatter_k(const int* __restrict__ srcA, const int* __restrict__ dstA,
                          int E, int* __restrict__ cur, int* __restrict__ csr) {
    int e = blockIdx.x * blockDim.x + threadIdx.x;
    if (e < E) {
        int p = atomicAdd(&cur[dstA[e]], 1);
        csr[p] = srcA[e];
    }
}

__global__ void selfloop_k(const int* __restrict__ offs, int* __restrict__ csr, int N) {
    int n = blockIdx.x * blockDim.x + threadIdx.x;
    if (n < N) csr[offs[n + 1] - 1] = n;
}

// ---------------------------------------------------------------------------
// Attention score vectors
// ---------------------------------------------------------------------------
__global__ void att1(const unsigned short* __restrict__ h1b, const float* __restrict__ atts,
                     const float* __restrict__ attd, float* __restrict__ as1,
                     float* __restrict__ ad1, int N) {
    int idx = blockIdx.x * blockDim.x + threadIdx.x;
    if (idx >= N * HEADS) return;
    int n = idx >> 2, h = idx & 3;
    const unsigned short* row = h1b + (size_t)n * 128 + h * 32;
    float ss = 0.f, dd = 0.f;
    #pragma unroll
    for (int c = 0; c < 32; c++) {
        float v = bfu2f(row[c]);
        ss += v * atts[h * 32 + c];
        dd += v * attd[h * 32 + c];
    }
    as1[idx] = ss; ad1[idx] = dd;
}

__global__ void att2(const float* __restrict__ h2r2, const float* __restrict__ atts,
                     const float* __restrict__ attd, float* __restrict__ as2,
                     float* __restrict__ ad2, int N) {
    int n = blockIdx.x * blockDim.x + threadIdx.x;
    if (n >= N) return;
    const float* row = h2r2 + (size_t)n * 80;
    float ss = 0.f, dd = 0.f;
    #pragma unroll
    for (int c = 0; c < OUTC; c++) {
        float v = row[c];
        ss += v * atts[c];
        dd += v * attd[c];
    }
    as2[n] = ss; ad2[n] = dd;
}

// ---------------------------------------------------------------------------
// GAT1 aggregation: one WAVE per node (4 nodes / 256-thread block).
// Thread t owns channels {2t, 2t+1}; head h = t>>4. Per-head max via 16-lane
// butterfly, then fused den+acc serial pass (bf16 gather of h1).
// ---------------------------------------------------------------------------
__global__ __launch_bounds__(256) void gat1_agg(const unsigned short* __restrict__ h1b,
                                                const float* __restrict__ r1,
                                                const float* __restrict__ as1,
                                                const float* __restrict__ ad1,
                                                const int* __restrict__ offs,
                                                const int* __restrict__ csr,
                                                const float* __restrict__ gb,
                                                const float* __restrict__ rb,
                                                float* __restrict__ outh, int N) {
    int n = blockIdx.x * 4 + (threadIdx.x >> 6);
    if (n >= N) return;
    int t = threadIdx.x & 63;
    int h = t >> 4;
    int l16 = t & 15;
    int beg = offs[n], d = offs[n + 1] - beg;
    float adst = ad1[n * HEADS + h];

    float mx = -INFINITY;
    for (int j = l16; j < d; j += 16) {
        int s = csr[beg + j];
        float v = as1[s * HEADS + h] + adst;
        v = v >= 0.f ? v : SLOPE * v;
        mx = fmaxf(mx, v);
    }
    #pragma unroll
    for (int o = 8; o; o >>= 1) mx = fmaxf(mx, __shfl_xor(mx, o, 16));

    float den = 0.f;
    float a0 = 0.f, a1 = 0.f;
    for (int j = 0; j < d; j++) {
        int s = csr[beg + j];
        float v = as1[s * HEADS + h] + adst;
        v = v >= 0.f ? v : SLOPE * v;
        float w = __expf(v - mx);
        den += w;
        ushort2 hv = *(const ushort2*)(h1b + (size_t)s * 128 + 2 * t);
        a0 += w * bfu2f(hv.x);
        a1 += w * bfu2f(hv.y);
    }
    den = fmaxf(den, 1e-16f);
    float inv = 1.f / den;
    float2 rv = *(const float2*)(r1 + (size_t)n * 128 + 2 * t);
    float o0 = fmaxf(a0 * inv + gb[2 * t]     + rb[2 * t]     + rv.x, 0.f);
    float o1 = fmaxf(a1 * inv + gb[2 * t + 1] + rb[2 * t + 1] + rv.y, 0.f);
    float2 ov = {o0, o1};
    *(float2*)(outh + (size_t)n * 128 + 2 * t) = ov;
}

// ---------------------------------------------------------------------------
// GAT2 aggregation: one WAVE per node (4 nodes / 256-thread block), 1 head.
// ---------------------------------------------------------------------------
__global__ __launch_bounds__(256) void gat2_agg(const unsigned short* __restrict__ h2b,
                                                const float* __restrict__ h2r2,
                                                const float* __restrict__ as2,
                                                const float* __restrict__ ad2,
                                                const int* __restrict__ offs,
                                                const int* __restrict__ csr,
                                                const float* __restrict__ gb,
                                                float* __restrict__ out, int N) {
    int n = blockIdx.x * 4 + (threadIdx.x >> 6);
    if (n >= N) return;
    int t = threadIdx.x & 63;
    int beg = offs[n], d = offs[n + 1] - beg;
    float adst = ad2[n];

    float mx = -INFINITY;
    for (int j = t; j < d; j += 64) {
        int s = csr[beg + j];
        float v = as2[s] + adst;
        v = v >= 0.f ? v : SLOPE * v;
        mx = fmaxf(mx, v);
    }
    #pragma unroll
    for (int o = 32; o; o >>= 1) mx = fmaxf(mx, __shfl_xor(mx, o, 64));

    float den = 0.f, acc = 0.f;
    for (int j = 0; j < d; j++) {
        int s = csr[beg + j];
        float v = as2[s] + adst;
        v = v >= 0.f ? v : SLOPE * v;
        float w = __expf(v - mx);
        den += w;
        if (t < OUTC) acc += w * bfu2f(h2b[(size_t)s * OUTC + t]);
    }
    den = fmaxf(den, 1e-16f);
    if (t < OUTC)
        out[(size_t)n * OUTC + t] = acc / den + gb[t] + h2r2[(size_t)n * 80 + 40 + t];
}

// ---------------------------------------------------------------------------
// Launcher
// ---------------------------------------------------------------------------
extern "C" void kernel_launch(void* const* d_in, const int* in_sizes, int n_in,
                              void* d_out, int out_size, void* d_ws, size_t ws_size,
                              hipStream_t stream) {
    const float* x      = (const float*)d_in[0];
    const int*   ei     = (const int*)d_in[1];
    const float* ae_w1  = (const float*)d_in[2];
    const float* ae_b1  = (const float*)d_in[3];
    const float* ae_w2  = (const float*)d_in[4];
    const float* ae_b2  = (const float*)d_in[5];
    const float* gat1_w = (const float*)d_in[6];
    const float* g1as   = (const float*)d_in[7];
    const float* g1ad   = (const float*)d_in[8];
    const float* g1b    = (const float*)d_in[9];
    const float* gat2_w = (const float*)d_in[10];
    const float* g2as   = (const float*)d_in[11];
    const float* g2ad   = (const float*)d_in[12];
    const float* g2b    = (const float*)d_in[13];
    const float* res1_w = (const float*)d_in[14];
    const float* res1_b = (const float*)d_in[15];
    const float* res2_w = (const float*)d_in[16];
    const float* res2_b = (const float*)d_in[17];
    float* out = (float*)d_out;

    const int Nn = in_sizes[0] / 512;       // 50000 nodes
    const int E  = in_sizes[1] / 2;         // 800000 edges

    const int* srcA = ei;
    const int* dstA = ei + E;

    // ---- workspace layout ----
    char* W = (char*)d_ws;
    size_t off = 0;
    auto alloc = [&](size_t bytes) { char* p = W + off; off += (bytes + 255) & ~(size_t)255; return p; };

    // Region1: xb bf16 [Nn,512] (51.2 MB); after fc1 reused as hbuf/h2r2/h2bf
    char* reg1 = alloc((size_t)Nn * 512 * 2);
    unsigned short* xb = (unsigned short*)reg1;
    float* hbuf = (float*)reg1;                                  // [Nn,128] f32
    float* h2r2 = (float*)(reg1 + (size_t)Nn * 128 * 4);         // [Nn,80] f32
    unsigned short* h2bf = (unsigned short*)(reg1 + (size_t)Nn * 208 * 4); // [Nn,40]

    // Region2: y1b bf16 [Nn,256] (25.6 MB); after fc2 reused as r1 f32 [Nn,128]
    char* reg2 = alloc((size_t)Nn * 256 * 2);
    unsigned short* y1b = (unsigned short*)reg2;
    float* r1 = (float*)reg2;

    // Region3: xeb bf16 [Nn,256]
    unsigned short* xeb = (unsigned short*)alloc((size_t)Nn * 256 * 2);
    // Region4: h1b bf16 [Nn,128]
    unsigned short* h1b = (unsigned short*)alloc((size_t)Nn * 128 * 2);

    short* w1Thi = (short*)alloc(256 * 512 * 2);
    short* w1Tlo = (short*)alloc(256 * 512 * 2);
    short* w2Thi = (short*)alloc(256 * 256 * 2);
    short* w2Tlo = (short*)alloc(256 * 256 * 2);
    short* wc1hi = (short*)alloc(256 * 256 * 2);
    short* wc1lo = (short*)alloc(256 * 256 * 2);
    float* wc2   = (float*)alloc(128 * 80 * 4);
    float* cb2   = (float*)alloc(128 * 4);
    float* as1   = (float*)alloc((size_t)Nn * HEADS * 4);
    float* ad1   = (float*)alloc((size_t)Nn * HEADS * 4);
    float* as2   = (float*)alloc((size_t)Nn * 4);
    float* ad2   = (float*)alloc((size_t)Nn * 4);
    int* deg  = (int*)alloc((size_t)Nn * 4);
    int* offs = (int*)alloc((size_t)(Nn + 1) * 4);
    int* cur  = (int*)alloc((size_t)Nn * 4);
    int* part = (int*)alloc(256 * 4);
    int* csr  = (int*)alloc((size_t)(E + Nn) * 4);

    // ---- weight prep ----
    wt_split<<<(512 * 256 + 255) / 256, 256, 0, stream>>>(ae_w1, 512, 256, w1Thi, w1Tlo);
    wt_split<<<(256 * 256 + 255) / 256, 256, 0, stream>>>(ae_w2, 256, 256, w2Thi, w2Tlo);
    wt_split2<<<(256 * 256 + 255) / 256, 256, 0, stream>>>(gat1_w, res1_w, 256, 128, wc1hi, wc1lo);
    build_wc2<<<(128 * 80 + 255) / 256, 256, 0, stream>>>(gat2_w, res2_w, res2_b, wc2, cb2);

    // ---- CSR build ----
    hipMemsetAsync(deg, 0, (size_t)Nn * sizeof(int), stream);
    count_deg<<<(E + 255) / 256, 256, 0, stream>>>(dstA, E, deg);
    int nb = (Nn + 1023) / 1024;
    scan_part<<<nb, 256, 0, stream>>>(deg, Nn, part);
    scan_base<<<1, 64, 0, stream>>>(part, nb, offs);
    scan_final<<<nb, 256, 0, stream>>>(deg, Nn, part, offs, cur);
    scatter_k<<<(E + 255) / 256, 256, 0, stream>>>(srcA, dstA, E, cur, csr);
    selfloop_k<<<(Nn + 255) / 256, 256, 0, stream>>>(offs, csr, Nn);

    // ---- x -> bf16 ----
    long xtotal = (long)Nn * 512;
    x2bf<<<(int)((xtotal / 8 + 255) / 256), 256, 0, stream>>>(x, (unsigned int*)xb, xtotal);

    const int gy = (Nn + 127) / 128;   // 391

    // ---- fc1: relu(xb @ ae_w1 + b1) -> y1b bf16 ----
    gemm2<0><<<dim3(2, gy), 256, 0, stream>>>(
        (const short*)xb, w1Thi, w1Tlo, ae_b1, y1b, nullptr, Nn, 256, 512);

    // ---- fc2: relu(y1b @ ae_w2 + b2) -> xeb bf16 ----
    gemm2<0><<<dim3(2, gy), 256, 0, stream>>>(
        (const short*)y1b, w2Thi, w2Tlo, ae_b2, xeb, nullptr, Nn, 256, 256);

    // ---- gatres1: xeb @ [gat1_w | res1_w] -> h1b bf16 [Nn,128], r1 f32 [Nn,128] ----
    gemm2<1><<<dim3(2, gy), 256, 0, stream>>>(
        (const short*)xeb, wc1hi, wc1lo, nullptr, h1b, r1, Nn, 256, 256);

    att1<<<(Nn * HEADS + 255) / 256, 256, 0, stream>>>(h1b, g1as, g1ad, as1, ad1, Nn);
    gat1_agg<<<(Nn + 3) / 4, 256, 0, stream>>>(h1b, r1, as1, ad1, offs, csr, g1b, res1_b, hbuf, Nn);

    // ---- gatres2 (f32): hbuf @ [gat2_w | res2_w] + [0|res2_b] -> h2r2 [Nn,80] ----
    gemm_bias<<<dim3(2, (Nn + 63) / 64), 256, 0, stream>>>(hbuf, wc2, cb2, h2r2, h2bf, Nn, 80, 128);

    att2<<<(Nn + 255) / 256, 256, 0, stream>>>(h2r2, g2as, g2ad, as2, ad2, Nn);
    gat2_agg<<<(Nn + 3) / 4, 256, 0, stream>>>(h2bf, h2r2, as2, ad2, offs, csr, g2b, out, Nn);
}

// Round 5
// 465.364 us; speedup vs baseline: 1.1546x; 1.0665x over previous
//
#include <hip/hip_runtime.h>
#include <hip/hip_bf16.h>
#include <math.h>

#define HEADS 4
#define OUTC 40
#define SLOPE 0.2f

typedef __attribute__((ext_vector_type(8))) short bf16x8;
typedef __attribute__((ext_vector_type(4))) float f32x4;

__device__ __forceinline__ short f2bf(float f) {
    unsigned u = __float_as_uint(f);
    unsigned r = (u + 0x7FFFu + ((u >> 16) & 1u)) >> 16;
    return (short)r;
}
__device__ __forceinline__ float bf2f(short s) {
    return __uint_as_float(((unsigned)(unsigned short)s) << 16);
}
__device__ __forceinline__ float bfu2f(unsigned short s) {
    return __uint_as_float(((unsigned)s) << 16);
}

typedef const __attribute__((address_space(1))) unsigned int gu32;
typedef __attribute__((address_space(3))) unsigned int lu32;
__device__ __forceinline__ void gll16(const void* src, void* lds) {
    __builtin_amdgcn_global_load_lds((gu32*)src, (lu32*)lds, 16, 0, 0);
}

// ---------------------------------------------------------------------------
// x -> bf16 conversion (pure BW pass)
// ---------------------------------------------------------------------------
__global__ void x2bf(const float* __restrict__ x, unsigned int* __restrict__ xb,
                     long total) {
    long i = ((long)blockIdx.x * blockDim.x + threadIdx.x) * 8;
    if (i >= total) return;
    float4 a = *(const float4*)(x + i);
    float4 b = *(const float4*)(x + i + 4);
    uint4 o;
    o.x = (unsigned short)f2bf(a.x) | ((unsigned)(unsigned short)f2bf(a.y) << 16);
    o.y = (unsigned short)f2bf(a.z) | ((unsigned)(unsigned short)f2bf(a.w) << 16);
    o.z = (unsigned short)f2bf(b.x) | ((unsigned)(unsigned short)f2bf(b.y) << 16);
    o.w = (unsigned short)f2bf(b.z) | ((unsigned)(unsigned short)f2bf(b.w) << 16);
    *(uint4*)(xb + i / 2) = o;
}

// ---------------------------------------------------------------------------
// bf16-A MFMA GEMM: C[M,N] = A[M,K] @ B[K,N]. A single bf16 plane; B hi/lo
// planes [N][K]. BM=BN=128, BK=64, 4 waves, 48 KB LDS.
// EPI=0: relu(acc+bias) -> bf16. EPI=1: cols<128 -> bf16 Obf; cols>=128 -> f32 Of.
// ---------------------------------------------------------------------------
template<int EPI>
__global__ __launch_bounds__(256) void gemm2(
    const short* __restrict__ A,
    const short* __restrict__ Bhi, const short* __restrict__ Blo,
    const float* __restrict__ bias,
    unsigned short* __restrict__ Obf, float* __restrict__ Of,
    int M, int N, int K)
{
    __shared__ short smem[24576];          // 48 KB
    short* As  = smem;
    short* BsH = smem + 8192;
    short* BsL = smem + 16384;

    const int tid = threadIdx.x;
    const int wid = tid >> 6, lane = tid & 63;
    const int bm = blockIdx.y * 128, bn = blockIdx.x * 128;
    const int wm = wid >> 1, wn = wid & 1;
    const int rA = lane & 15, kb = lane >> 4;

    f32x4 acc[4][4];
    #pragma unroll
    for (int i = 0; i < 4; i++)
        #pragma unroll
        for (int j = 0; j < 4; j++)
            acc[i][j] = (f32x4){0.f, 0.f, 0.f, 0.f};

    const int KT = K >> 6;
    for (int kt = 0; kt < KT; kt++) {
        const int k0 = kt << 6;
        #pragma unroll
        for (int it = 0; it < 4; it++) {
            int g = it * 256 + tid;
            int row = g >> 3, gr = g & 7;
            int gsrc = gr ^ (row & 7);
            int grow = bm + row; if (grow > M - 1) grow = M - 1;
            gll16(A + (size_t)grow * K + k0 + gsrc * 8,
                  As + (it * 256 + wid * 64) * 8);
        }
        #pragma unroll
        for (int p = 0; p < 2; p++) {
            const short* Bp = p ? Blo : Bhi;
            short* Ds = p ? BsL : BsH;
            #pragma unroll
            for (int it = 0; it < 4; it++) {
                int g = it * 256 + tid;
                int row = g >> 3, gr = g & 7;
                int gsrc = gr ^ (row & 7);
                gll16(Bp + (size_t)(bn + row) * K + k0 + gsrc * 8,
                      Ds + (it * 256 + wid * 64) * 8);
            }
        }
        __syncthreads();
        #pragma unroll
        for (int kc = 0; kc < 2; kc++) {
            bf16x8 a[4], bh[4], bl[4];
            #pragma unroll
            for (int mi = 0; mi < 4; mi++) {
                int r = wm * 64 + mi * 16 + rA;
                int off = r * 64 + (((kc * 4 + kb) ^ (r & 7)) * 8);
                a[mi] = *(const bf16x8*)(As + off);
            }
            #pragma unroll
            for (int ni = 0; ni < 4; ni++) {
                int r = wn * 64 + ni * 16 + rA;
                int off = r * 64 + (((kc * 4 + kb) ^ (r & 7)) * 8);
                bh[ni] = *(const bf16x8*)(BsH + off);
                bl[ni] = *(const bf16x8*)(BsL + off);
            }
            #pragma unroll
            for (int mi = 0; mi < 4; mi++)
                #pragma unroll
                for (int ni = 0; ni < 4; ni++) {
                    acc[mi][ni] = __builtin_amdgcn_mfma_f32_16x16x32_bf16(a[mi], bh[ni], acc[mi][ni], 0, 0, 0);
                    acc[mi][ni] = __builtin_amdgcn_mfma_f32_16x16x32_bf16(a[mi], bl[ni], acc[mi][ni], 0, 0, 0);
                }
        }
        __syncthreads();
    }

    #pragma unroll
    for (int ni = 0; ni < 4; ni++) {
        int col = bn + wn * 64 + ni * 16 + rA;
        float bv = (EPI == 0) ? bias[col] : 0.f;
        #pragma unroll
        for (int mi = 0; mi < 4; mi++) {
            #pragma unroll
            for (int j = 0; j < 4; j++) {
                int row = bm + wm * 64 + mi * 16 + kb * 4 + j;
                if (row < M) {
                    float v = acc[mi][ni][j];
                    if (EPI == 0) {
                        v = fmaxf(v + bv, 0.f);
                        Obf[(size_t)row * N + col] = (unsigned short)f2bf(v);
                    } else {
                        if (col < 128) Obf[(size_t)row * 128 + col] = (unsigned short)f2bf(v);
                        else           Of[(size_t)row * 128 + (col - 128)] = v;
                    }
                }
            }
        }
    }
}

// ---------------------------------------------------------------------------
// f32 vector GEMM (N=80 merged gat2/res2) + bf16 shadow of cols<40.
// ---------------------------------------------------------------------------
__global__ __launch_bounds__(256) void gemm_bias(const float* __restrict__ A,
                                                 const float* __restrict__ B,
                                                 const float* __restrict__ bias,
                                                 float* __restrict__ C,
                                                 unsigned short* __restrict__ Cbf,
                                                 int M, int N, int K) {
    __shared__ float As[16][65];
    __shared__ float Bs[16][64];
    int tid = threadIdx.x;
    int tx = tid & 15, ty = tid >> 4;
    int bm = blockIdx.y * 64, bn = blockIdx.x * 64;
    int arow = tid >> 2, acol = (tid & 3) << 2;
    int brow = tid >> 4, bcol = (tid & 15) << 2;
    bool fullM = (bm + 64 <= M);
    bool fullN = (bn + 64 <= N);
    float acc[4][4] = {{0.f}};

    for (int k0 = 0; k0 < K; k0 += 16) {
        if (fullM) {
            const float4 av = *(const float4*)(A + (size_t)(bm + arow) * K + (k0 + acol));
            As[acol + 0][arow] = av.x; As[acol + 1][arow] = av.y;
            As[acol + 2][arow] = av.z; As[acol + 3][arow] = av.w;
        } else {
            int r = bm + arow;
            #pragma unroll
            for (int i = 0; i < 4; i++)
                As[acol + i][arow] = (r < M) ? A[(size_t)r * K + k0 + acol + i] : 0.f;
        }
        if (fullN) {
            *(float4*)(&Bs[brow][bcol]) = *(const float4*)(B + (size_t)(k0 + brow) * N + (bn + bcol));
        } else {
            #pragma unroll
            for (int i = 0; i < 4; i++) {
                int c = bn + bcol + i;
                Bs[brow][bcol + i] = (c < N) ? B[(size_t)(k0 + brow) * N + c] : 0.f;
            }
        }
        __syncthreads();
        #pragma unroll
        for (int kk = 0; kk < 16; kk++) {
            float a[4], b[4];
            #pragma unroll
            for (int i = 0; i < 4; i++) a[i] = As[kk][ty * 4 + i];
            #pragma unroll
            for (int j = 0; j < 4; j++) b[j] = Bs[kk][tx * 4 + j];
            #pragma unroll
            for (int i = 0; i < 4; i++)
                #pragma unroll
                for (int j = 0; j < 4; j++) acc[i][j] += a[i] * b[j];
        }
        __syncthreads();
    }

    #pragma unroll
    for (int i = 0; i < 4; i++) {
        int r = bm + ty * 4 + i;
        if (r < M) {
            #pragma unroll
            for (int j = 0; j < 4; j++) {
                int c = bn + tx * 4 + j;
                if (c < N) {
                    float v = acc[i][j] + (bias ? bias[c] : 0.f);
                    C[(size_t)r * N + c] = v;
                    if (Cbf && c < OUTC)
                        Cbf[(size_t)r * OUTC + c] = (unsigned short)f2bf(v);
                }
            }
        }
    }
}

// ---------------------------------------------------------------------------
// Weight conversion
// ---------------------------------------------------------------------------
__global__ void wt_split(const float* __restrict__ Wm, int K, int Nn,
                         short* __restrict__ hi, short* __restrict__ lo) {
    int idx = blockIdx.x * blockDim.x + threadIdx.x;
    if (idx >= K * Nn) return;
    int n = idx / K, k = idx - n * K;
    float v = Wm[(size_t)k * Nn + n];
    short h = f2bf(v);
    hi[idx] = h; lo[idx] = f2bf(v - bf2f(h));
}

__global__ void wt_split2(const float* __restrict__ Wg, const float* __restrict__ Wr,
                          int K, int Nh, short* __restrict__ hi, short* __restrict__ lo) {
    int idx = blockIdx.x * blockDim.x + threadIdx.x;
    if (idx >= K * 2 * Nh) return;
    int n = idx / K, k = idx - n * K;
    float v = (n < Nh) ? Wg[(size_t)k * Nh + n] : Wr[(size_t)k * Nh + (n - Nh)];
    short h = f2bf(v);
    hi[idx] = h; lo[idx] = f2bf(v - bf2f(h));
}

__global__ void build_wc2(const float* __restrict__ g2w, const float* __restrict__ r2w,
                          const float* __restrict__ r2b,
                          float* __restrict__ wc2, float* __restrict__ cb2) {
    int idx = blockIdx.x * blockDim.x + threadIdx.x;
    if (idx < 128 * 80) {
        int k = idx / 80, n = idx - k * 80;
        wc2[idx] = (n < 40) ? g2w[k * 40 + n] : r2w[k * 40 + (n - 40)];
    }
    if (idx < 80) cb2[idx] = (idx < 40) ? 0.f : r2b[idx - 40];
}

// ---------------------------------------------------------------------------
// CSR build (csr + dstslot)
// ---------------------------------------------------------------------------
__global__ void count_deg(const int* __restrict__ dstA, int E, int* __restrict__ deg) {
    int e = blockIdx.x * blockDim.x + threadIdx.x;
    if (e < E) atomicAdd(&deg[dstA[e]], 1);
}

__global__ void scan_part(const int* __restrict__ deg, int N, int* __restrict__ part) {
    __shared__ int s[256];
    int b = blockIdx.x, t = threadIdx.x;
    int i0 = b * 1024 + t * 4;
    int sum = 0;
    #pragma unroll
    for (int j = 0; j < 4; j++) { int i = i0 + j; if (i < N) sum += deg[i] + 1; }
    s[t] = sum; __syncthreads();
    for (int o = 128; o; o >>= 1) { if (t < o) s[t] += s[t + o]; __syncthreads(); }
    if (t == 0) part[b] = s[0];
}

__global__ void scan_base(int* __restrict__ part, int nb, int* __restrict__ offs) {
    int t = threadIdx.x;
    int v = (t < nb) ? part[t] : 0;
    int v0 = v;
    for (int o = 1; o < 64; o <<= 1) {
        int u = __shfl_up(v, o, 64);
        if (t >= o) v += u;
    }
    if (t < nb) part[t] = v - v0;   // exclusive
    if (t == 0) offs[0] = 0;
}

__global__ void scan_final(const int* __restrict__ deg, int N, const int* __restrict__ part,
                           int* __restrict__ offs, int* __restrict__ cur) {
    __shared__ int s[256];
    int b = blockIdx.x, t = threadIdx.x;
    int i0 = b * 1024 + t * 4;
    int v[4]; int sum = 0;
    #pragma unroll
    for (int j = 0; j < 4; j++) { int i = i0 + j; v[j] = (i < N) ? deg[i] + 1 : 0; sum += v[j]; }
    s[t] = sum; __syncthreads();
    for (int o = 1; o < 256; o <<= 1) {
        int add = (t >= o) ? s[t - o] : 0;
        __syncthreads();
        s[t] += add;
        __syncthreads();
    }
    int excl = s[t] - sum + part[b];
    #pragma unroll
    for (int j = 0; j < 4; j++) {
        int i = i0 + j;
        if (i < N) { cur[i] = excl; offs[i + 1] = excl + v[j]; excl += v[j]; }
    }
}

__global__ void scatter_k(const int* __restrict__ srcA, const int* __restrict__ dstA,
                          int E, int* __restrict__ cur, int* __restrict__ csr,
                          int* __restrict__ dstslot) {
    int e = blockIdx.x * blockDim.x + threadIdx.x;
    if (e < E) {
        int dn = dstA[e];
        int p = atomicAdd(&cur[dn], 1);
        csr[p] = srcA[e];
        dstslot[p] = dn;
    }
}

__global__ void selfloop_k(const int* __restrict__ offs, int* __restrict__ csr,
                           int* __restrict__ dstslot, int N) {
    int n = blockIdx.x * blockDim.x + threadIdx.x;
    if (n < N) { int p = offs[n + 1] - 1; csr[p] = n; dstslot[p] = n; }
}

// ---------------------------------------------------------------------------
// Attention score vectors
// ---------------------------------------------------------------------------
__global__ void att1(const unsigned short* __restrict__ h1b, const float* __restrict__ atts,
                     const float* __restrict__ attd, float* __restrict__ as1,
                     float* __restrict__ ad1, int N) {
    int idx = blockIdx.x * blockDim.x + threadIdx.x;
    if (idx >= N * HEADS) return;
    int n = idx >> 2, h = idx & 3;
    const unsigned short* row = h1b + (size_t)n * 128 + h * 32;
    float ss = 0.f, dd = 0.f;
    #pragma unroll
    for (int c4 = 0; c4 < 4; c4++) {
        uint4 v = *(const uint4*)(row + c4 * 8);
        float4 ws1 = *(const float4*)(atts + h * 32 + c4 * 8);
        float4 ws2 = *(const float4*)(atts + h * 32 + c4 * 8 + 4);
        float4 wd1 = *(const float4*)(attd + h * 32 + c4 * 8);
        float4 wd2 = *(const float4*)(attd + h * 32 + c4 * 8 + 4);
        float e0 = bfu2f((unsigned short)(v.x & 0xFFFF)), e1 = bfu2f((unsigned short)(v.x >> 16));
        float e2 = bfu2f((unsigned short)(v.y & 0xFFFF)), e3 = bfu2f((unsigned short)(v.y >> 16));
        float e4 = bfu2f((unsigned short)(v.z & 0xFFFF)), e5 = bfu2f((unsigned short)(v.z >> 16));
        float e6 = bfu2f((unsigned short)(v.w & 0xFFFF)), e7 = bfu2f((unsigned short)(v.w >> 16));
        ss += e0*ws1.x + e1*ws1.y + e2*ws1.z + e3*ws1.w + e4*ws2.x + e5*ws2.y + e6*ws2.z + e7*ws2.w;
        dd += e0*wd1.x + e1*wd1.y + e2*wd1.z + e3*wd1.w + e4*wd2.x + e5*wd2.y + e6*wd2.z + e7*wd2.w;
    }
    as1[idx] = ss; ad1[idx] = dd;
}

__global__ void att2(const float* __restrict__ h2r2, const float* __restrict__ atts,
                     const float* __restrict__ attd, float* __restrict__ as2,
                     float* __restrict__ ad2, int N) {
    int n = blockIdx.x * blockDim.x + threadIdx.x;
    if (n >= N) return;
    const float* row = h2r2 + (size_t)n * 80;
    float ss = 0.f, dd = 0.f;
    #pragma unroll
    for (int c = 0; c < OUTC; c += 4) {
        float4 v = *(const float4*)(row + c);
        float4 ws = *(const float4*)(atts + c);
        float4 wd = *(const float4*)(attd + c);
        ss += v.x*ws.x + v.y*ws.y + v.z*ws.z + v.w*ws.w;
        dd += v.x*wd.x + v.y*wd.y + v.z*wd.z + v.w*wd.w;
    }
    as2[n] = ss; ad2[n] = dd;
}

// ---------------------------------------------------------------------------
// Per-node max + 1/den, layer 1 (4 heads). Wave per node; lanes (h, l16).
// ---------------------------------------------------------------------------
__global__ __launch_bounds__(256) void maxden1(const float* __restrict__ as1,
                                               const float* __restrict__ ad1,
                                               const int* __restrict__ offs,
                                               const int* __restrict__ csr,
                                               float* __restrict__ m1,
                                               float* __restrict__ invden1, int N) {
    int n = blockIdx.x * 4 + (threadIdx.x >> 6);
    if (n >= N) return;
    int t = threadIdx.x & 63;
    int h = t >> 4, l = t & 15;
    int beg = offs[n], d = offs[n + 1] - beg;
    float adst = ad1[n * 4 + h];
    float mx = -INFINITY;
    for (int j = l; j < d; j += 16) {
        int s = csr[beg + j];
        float v = as1[s * 4 + h] + adst;
        v = v >= 0.f ? v : SLOPE * v;
        mx = fmaxf(mx, v);
    }
    #pragma unroll
    for (int o = 8; o; o >>= 1) mx = fmaxf(mx, __shfl_xor(mx, o, 16));
    float den = 0.f;
    for (int j = l; j < d; j += 16) {
        int s = csr[beg + j];
        float v = as1[s * 4 + h] + adst;
        v = v >= 0.f ? v : SLOPE * v;
        den += __expf(v - mx);
    }
    #pragma unroll
    for (int o = 8; o; o >>= 1) den += __shfl_xor(den, o, 16);
    if (l == 0) {
        m1[n * 4 + h] = mx;
        invden1[n * 4 + h] = 1.f / fmaxf(den, 1e-16f);
    }
}

// Layer 2 (1 head), 64-lane strided.
__global__ __launch_bounds__(256) void maxden2(const float* __restrict__ as2,
                                               const float* __restrict__ ad2,
                                               const int* __restrict__ offs,
                                               const int* __restrict__ csr,
                                               float* __restrict__ m2,
                                               float* __restrict__ invden2, int N) {
    int n = blockIdx.x * 4 + (threadIdx.x >> 6);
    if (n >= N) return;
    int t = threadIdx.x & 63;
    int beg = offs[n], d = offs[n + 1] - beg;
    float adst = ad2[n];
    float mx = -INFINITY;
    for (int j = t; j < d; j += 64) {
        int s = csr[beg + j];
        float v = as2[s] + adst;
        v = v >= 0.f ? v : SLOPE * v;
        mx = fmaxf(mx, v);
    }
    #pragma unroll
    for (int o = 32; o; o >>= 1) mx = fmaxf(mx, __shfl_xor(mx, o, 64));
    float den = 0.f;
    for (int j = t; j < d; j += 64) {
        int s = csr[beg + j];
        float v = as2[s] + adst;
        v = v >= 0.f ? v : SLOPE * v;
        den += __expf(v - mx);
    }
    #pragma unroll
    for (int o = 32; o; o >>= 1) den += __shfl_xor(den, o, 64);
    if (t == 0) {
        m2[n] = mx;
        invden2[n] = 1.f / fmaxf(den, 1e-16f);
    }
}

// ---------------------------------------------------------------------------
// Edge-parallel normalized alpha, layer 1: thread per (slot, head).
// ---------------------------------------------------------------------------
__global__ void alpha1_k(const int* __restrict__ csr, const int* __restrict__ dstslot,
                         const float* __restrict__ as1, const float* __restrict__ ad1,
                         const float* __restrict__ m1, const float* __restrict__ invden1,
                         float* __restrict__ a1, int Etot) {
    int gid = blockIdx.x * blockDim.x + threadIdx.x;
    if (gid >= Etot * 4) return;
    int i = gid >> 2, h = gid & 3;
    int s = csr[i], dn = dstslot[i];
    float v = as1[s * 4 + h] + ad1[dn * 4 + h];
    v = v >= 0.f ? v : SLOPE * v;
    a1[gid] = __expf(v - m1[dn * 4 + h]) * invden1[dn * 4 + h];
}

// Layer 2: thread per slot.
__global__ void alpha2_k(const int* __restrict__ csr, const int* __restrict__ dstslot,
                         const float* __restrict__ as2, const float* __restrict__ ad2,
                         const float* __restrict__ m2, const float* __restrict__ invden2,
                         float* __restrict__ a2, int Etot) {
    int i = blockIdx.x * blockDim.x + threadIdx.x;
    if (i >= Etot) return;
    int s = csr[i], dn = dstslot[i];
    float v = as2[s] + ad2[dn];
    v = v >= 0.f ? v : SLOPE * v;
    a2[i] = __expf(v - m2[dn]) * invden2[dn];
}

// ---------------------------------------------------------------------------
// GAT1 aggregation: wave per node; thread t owns ch {2t,2t+1}, head t>>4.
// Loop body: linear alpha/csr reads (1-ahead prefetch) + h1b gather + FMA.
// ---------------------------------------------------------------------------
__global__ __launch_bounds__(256) void gat1_agg(const unsigned short* __restrict__ h1b,
                                                const float* __restrict__ r1,
                                                const float* __restrict__ a1,
                                                const int* __restrict__ offs,
                                                const int* __restrict__ csr,
                                                const float* __restrict__ gb,
                                                const float* __restrict__ rb,
                                                float* __restrict__ outh, int N) {
    int n = blockIdx.x * 4 + (threadIdx.x >> 6);
    if (n >= N) return;
    int t = threadIdx.x & 63;
    int h = t >> 4;
    int beg = offs[n], d = offs[n + 1] - beg;

    float acc0 = 0.f, acc1 = 0.f;
    int s_cur = csr[beg];
    float w_cur = a1[(size_t)beg * 4 + h];
    for (int j = 0; j < d; j++) {
        int s_nxt = s_cur; float w_nxt = 0.f;
        if (j + 1 < d) {
            s_nxt = csr[beg + j + 1];
            w_nxt = a1[(size_t)(beg + j + 1) * 4 + h];
        }
        ushort2 hv = *(const ushort2*)(h1b + (size_t)s_cur * 128 + 2 * t);
        acc0 += w_cur * bfu2f(hv.x);
        acc1 += w_cur * bfu2f(hv.y);
        s_cur = s_nxt; w_cur = w_nxt;
    }
    float2 rv = *(const float2*)(r1 + (size_t)n * 128 + 2 * t);
    float2 gv = *(const float2*)(gb + 2 * t);
    float2 bv = *(const float2*)(rb + 2 * t);
    float o0 = fmaxf(acc0 + gv.x + bv.x + rv.x, 0.f);
    float o1 = fmaxf(acc1 + gv.y + bv.y + rv.y, 0.f);
    float2 ov = {o0, o1};
    *(float2*)(outh + (size_t)n * 128 + 2 * t) = ov;
}

// ---------------------------------------------------------------------------
// GAT2 aggregation: wave per node; lanes t<20 own ch {2t,2t+1}.
// ---------------------------------------------------------------------------
__global__ __launch_bounds__(256) void gat2_agg(const unsigned short* __restrict__ h2b,
                                                const float* __restrict__ h2r2,
                                                const float* __restrict__ a2,
                                                const int* __restrict__ offs,
                                                const int* __restrict__ csr,
                                                const float* __restrict__ gb,
                                                float* __restrict__ out, int N) {
    int n = blockIdx.x * 4 + (threadIdx.x >> 6);
    if (n >= N) return;
    int t = threadIdx.x & 63;
    int beg = offs[n], d = offs[n + 1] - beg;

    float acc0 = 0.f, acc1 = 0.f;
    int s_cur = csr[beg];
    float w_cur = a2[beg];
    for (int j = 0; j < d; j++) {
        int s_nxt = s_cur; float w_nxt = 0.f;
        if (j + 1 < d) {
            s_nxt = csr[beg + j + 1];
            w_nxt = a2[beg + j + 1];
        }
        if (t < 20) {
            ushort2 hv = *(const ushort2*)(h2b + (size_t)s_cur * OUTC + 2 * t);
            acc0 += w_cur * bfu2f(hv.x);
            acc1 += w_cur * bfu2f(hv.y);
        }
        s_cur = s_nxt; w_cur = w_nxt;
    }
    if (t < 20) {
        float2 rr = *(const float2*)(h2r2 + (size_t)n * 80 + 40 + 2 * t);
        float2 gv = *(const float2*)(gb + 2 * t);
        float2 ov = {acc0 + gv.x + rr.x, acc1 + gv.y + rr.y};
        *(float2*)(out + (size_t)n * OUTC + 2 * t) = ov;
    }
}

// ---------------------------------------------------------------------------
// Launcher
// ---------------------------------------------------------------------------
extern "C" void kernel_launch(void* const* d_in, const int* in_sizes, int n_in,
                              void* d_out, int out_size, void* d_ws, size_t ws_size,
                              hipStream_t stream) {
    const float* x      = (const float*)d_in[0];
    const int*   ei     = (const int*)d_in[1];
    const float* ae_w1  = (const float*)d_in[2];
    const float* ae_b1  = (const float*)d_in[3];
    const float* ae_w2  = (const float*)d_in[4];
    const float* ae_b2  = (const float*)d_in[5];
    const float* gat1_w = (const float*)d_in[6];
    const float* g1as   = (const float*)d_in[7];
    const float* g1ad   = (const float*)d_in[8];
    const float* g1b    = (const float*)d_in[9];
    const float* gat2_w = (const float*)d_in[10];
    const float* g2as   = (const float*)d_in[11];
    const float* g2ad   = (const float*)d_in[12];
    const float* g2b    = (const float*)d_in[13];
    const float* res1_w = (const float*)d_in[14];
    const float* res1_b = (const float*)d_in[15];
    const float* res2_w = (const float*)d_in[16];
    const float* res2_b = (const float*)d_in[17];
    float* out = (float*)d_out;

    const int Nn = in_sizes[0] / 512;       // 50000 nodes
    const int E  = in_sizes[1] / 2;         // 800000 edges
    const int Etot = E + Nn;

    const int* srcA = ei;
    const int* dstA = ei + E;

    // ---- workspace layout ----
    char* W = (char*)d_ws;
    size_t off = 0;
    auto alloc = [&](size_t bytes) { char* p = W + off; off += (bytes + 255) & ~(size_t)255; return p; };

    // Region1: xb bf16 [Nn,512]; after fc1 reused as hbuf/h2r2/h2bf
    char* reg1 = alloc((size_t)Nn * 512 * 2);
    unsigned short* xb = (unsigned short*)reg1;
    float* hbuf = (float*)reg1;                                  // [Nn,128] f32
    float* h2r2 = (float*)(reg1 + (size_t)Nn * 128 * 4);         // [Nn,80] f32
    unsigned short* h2bf = (unsigned short*)(reg1 + (size_t)Nn * 208 * 4); // [Nn,40]

    // Region2: y1b bf16 [Nn,256]; after fc2 reused as r1 f32 [Nn,128]
    char* reg2 = alloc((size_t)Nn * 256 * 2);
    unsigned short* y1b = (unsigned short*)reg2;
    float* r1 = (float*)reg2;

    unsigned short* xeb = (unsigned short*)alloc((size_t)Nn * 256 * 2);
    unsigned short* h1b = (unsigned short*)alloc((size_t)Nn * 128 * 2);

    short* w1Thi = (short*)alloc(256 * 512 * 2);
    short* w1Tlo = (short*)alloc(256 * 512 * 2);
    short* w2Thi = (short*)alloc(256 * 256 * 2);
    short* w2Tlo = (short*)alloc(256 * 256 * 2);
    short* wc1hi = (short*)alloc(256 * 256 * 2);
    short* wc1lo = (short*)alloc(256 * 256 * 2);
    float* wc2   = (float*)alloc(128 * 80 * 4);
    float* cb2   = (float*)alloc(128 * 4);
    float* as1   = (float*)alloc((size_t)Nn * HEADS * 4);
    float* ad1   = (float*)alloc((size_t)Nn * HEADS * 4);
    float* as2   = (float*)alloc((size_t)Nn * 4);
    float* ad2   = (float*)alloc((size_t)Nn * 4);
    float* m1    = (float*)alloc((size_t)Nn * HEADS * 4);
    float* iv1   = (float*)alloc((size_t)Nn * HEADS * 4);
    float* m2    = (float*)alloc((size_t)Nn * 4);
    float* iv2   = (float*)alloc((size_t)Nn * 4);
    float* a1    = (float*)alloc((size_t)Etot * HEADS * 4);     // 13.6 MB
    float* a2    = (float*)alloc((size_t)Etot * 4);             // 3.4 MB
    int* deg  = (int*)alloc((size_t)Nn * 4);
    int* offs = (int*)alloc((size_t)(Nn + 1) * 4);
    int* cur  = (int*)alloc((size_t)Nn * 4);
    int* part = (int*)alloc(256 * 4);
    int* csr  = (int*)alloc((size_t)Etot * 4);
    int* dsl  = (int*)alloc((size_t)Etot * 4);

    // ---- weight prep ----
    wt_split<<<(512 * 256 + 255) / 256, 256, 0, stream>>>(ae_w1, 512, 256, w1Thi, w1Tlo);
    wt_split<<<(256 * 256 + 255) / 256, 256, 0, stream>>>(ae_w2, 256, 256, w2Thi, w2Tlo);
    wt_split2<<<(256 * 256 + 255) / 256, 256, 0, stream>>>(gat1_w, res1_w, 256, 128, wc1hi, wc1lo);
    build_wc2<<<(128 * 80 + 255) / 256, 256, 0, stream>>>(gat2_w, res2_w, res2_b, wc2, cb2);

    // ---- CSR build ----
    hipMemsetAsync(deg, 0, (size_t)Nn * sizeof(int), stream);
    count_deg<<<(E + 255) / 256, 256, 0, stream>>>(dstA, E, deg);
    int nb = (Nn + 1023) / 1024;
    scan_part<<<nb, 256, 0, stream>>>(deg, Nn, part);
    scan_base<<<1, 64, 0, stream>>>(part, nb, offs);
    scan_final<<<nb, 256, 0, stream>>>(deg, Nn, part, offs, cur);
    scatter_k<<<(E + 255) / 256, 256, 0, stream>>>(srcA, dstA, E, cur, csr, dsl);
    selfloop_k<<<(Nn + 255) / 256, 256, 0, stream>>>(offs, csr, dsl, Nn);

    // ---- x -> bf16 ----
    long xtotal = (long)Nn * 512;
    x2bf<<<(int)((xtotal / 8 + 255) / 256), 256, 0, stream>>>(x, (unsigned int*)xb, xtotal);

    const int gy = (Nn + 127) / 128;   // 391

    // ---- fc1 / fc2 / gatres1 ----
    gemm2<0><<<dim3(2, gy), 256, 0, stream>>>(
        (const short*)xb, w1Thi, w1Tlo, ae_b1, y1b, nullptr, Nn, 256, 512);
    gemm2<0><<<dim3(2, gy), 256, 0, stream>>>(
        (const short*)y1b, w2Thi, w2Tlo, ae_b2, xeb, nullptr, Nn, 256, 256);
    gemm2<1><<<dim3(2, gy), 256, 0, stream>>>(
        (const short*)xeb, wc1hi, wc1lo, nullptr, h1b, r1, Nn, 256, 256);

    // ---- layer-1 attention path ----
    att1<<<(Nn * HEADS + 255) / 256, 256, 0, stream>>>(h1b, g1as, g1ad, as1, ad1, Nn);
    maxden1<<<(Nn + 3) / 4, 256, 0, stream>>>(as1, ad1, offs, csr, m1, iv1, Nn);
    alpha1_k<<<(Etot * 4 + 255) / 256, 256, 0, stream>>>(csr, dsl, as1, ad1, m1, iv1, a1, Etot);
    gat1_agg<<<(Nn + 3) / 4, 256, 0, stream>>>(h1b, r1, a1, offs, csr, g1b, res1_b, hbuf, Nn);

    // ---- gatres2 (f32) ----
    gemm_bias<<<dim3(2, (Nn + 63) / 64), 256, 0, stream>>>(hbuf, wc2, cb2, h2r2, h2bf, Nn, 80, 128);

    // ---- layer-2 attention path ----
    att2<<<(Nn + 255) / 256, 256, 0, stream>>>(h2r2, g2as, g2ad, as2, ad2, Nn);
    maxden2<<<(Nn + 3) / 4, 256, 0, stream>>>(as2, ad2, offs, csr, m2, iv2, Nn);
    alpha2_k<<<(Etot + 255) / 256, 256, 0, stream>>>(csr, dsl, as2, ad2, m2, iv2, a2, Etot);
    gat2_agg<<<(Nn + 3) / 4, 256, 0, stream>>>(h2bf, h2r2, a2, offs, csr, g2b, out, Nn);
}

// Round 6
// 416.406 us; speedup vs baseline: 1.2904x; 1.1176x over previous
//
#include <hip/hip_runtime.h>
#include <hip/hip_bf16.h>
#include <math.h>

#define HEADS 4
#define OUTC 40
#define SLOPE 0.2f

typedef __attribute__((ext_vector_type(8))) short bf16x8;
typedef __attribute__((ext_vector_type(4))) float f32x4;

__device__ __forceinline__ short f2bf(float f) {
    unsigned u = __float_as_uint(f);
    unsigned r = (u + 0x7FFFu + ((u >> 16) & 1u)) >> 16;
    return (short)r;
}
__device__ __forceinline__ float bf2f(short s) {
    return __uint_as_float(((unsigned)(unsigned short)s) << 16);
}
__device__ __forceinline__ float bfu2f(unsigned short s) {
    return __uint_as_float(((unsigned)s) << 16);
}

typedef const __attribute__((address_space(1))) unsigned int gu32;
typedef __attribute__((address_space(3))) unsigned int lu32;
__device__ __forceinline__ void gll16(const void* src, void* lds) {
    __builtin_amdgcn_global_load_lds((gu32*)src, (lu32*)lds, 16, 0, 0);
}

// ---------------------------------------------------------------------------
// x -> bf16 conversion (pure BW pass)
// ---------------------------------------------------------------------------
__global__ void x2bf(const float* __restrict__ x, unsigned int* __restrict__ xb,
                     long total) {
    long i = ((long)blockIdx.x * blockDim.x + threadIdx.x) * 8;
    if (i >= total) return;
    float4 a = *(const float4*)(x + i);
    float4 b = *(const float4*)(x + i + 4);
    uint4 o;
    o.x = (unsigned short)f2bf(a.x) | ((unsigned)(unsigned short)f2bf(a.y) << 16);
    o.y = (unsigned short)f2bf(a.z) | ((unsigned)(unsigned short)f2bf(a.w) << 16);
    o.z = (unsigned short)f2bf(b.x) | ((unsigned)(unsigned short)f2bf(b.y) << 16);
    o.w = (unsigned short)f2bf(b.z) | ((unsigned)(unsigned short)f2bf(b.w) << 16);
    *(uint4*)(xb + i / 2) = o;
}

// ---------------------------------------------------------------------------
// bf16-A MFMA GEMM (unchanged from round 5)
// ---------------------------------------------------------------------------
template<int EPI>
__global__ __launch_bounds__(256) void gemm2(
    const short* __restrict__ A,
    const short* __restrict__ Bhi, const short* __restrict__ Blo,
    const float* __restrict__ bias,
    unsigned short* __restrict__ Obf, float* __restrict__ Of,
    int M, int N, int K)
{
    __shared__ short smem[24576];          // 48 KB
    short* As  = smem;
    short* BsH = smem + 8192;
    short* BsL = smem + 16384;

    const int tid = threadIdx.x;
    const int wid = tid >> 6, lane = tid & 63;
    const int bm = blockIdx.y * 128, bn = blockIdx.x * 128;
    const int wm = wid >> 1, wn = wid & 1;
    const int rA = lane & 15, kb = lane >> 4;

    f32x4 acc[4][4];
    #pragma unroll
    for (int i = 0; i < 4; i++)
        #pragma unroll
        for (int j = 0; j < 4; j++)
            acc[i][j] = (f32x4){0.f, 0.f, 0.f, 0.f};

    const int KT = K >> 6;
    for (int kt = 0; kt < KT; kt++) {
        const int k0 = kt << 6;
        #pragma unroll
        for (int it = 0; it < 4; it++) {
            int g = it * 256 + tid;
            int row = g >> 3, gr = g & 7;
            int gsrc = gr ^ (row & 7);
            int grow = bm + row; if (grow > M - 1) grow = M - 1;
            gll16(A + (size_t)grow * K + k0 + gsrc * 8,
                  As + (it * 256 + wid * 64) * 8);
        }
        #pragma unroll
        for (int p = 0; p < 2; p++) {
            const short* Bp = p ? Blo : Bhi;
            short* Ds = p ? BsL : BsH;
            #pragma unroll
            for (int it = 0; it < 4; it++) {
                int g = it * 256 + tid;
                int row = g >> 3, gr = g & 7;
                int gsrc = gr ^ (row & 7);
                gll16(Bp + (size_t)(bn + row) * K + k0 + gsrc * 8,
                      Ds + (it * 256 + wid * 64) * 8);
            }
        }
        __syncthreads();
        #pragma unroll
        for (int kc = 0; kc < 2; kc++) {
            bf16x8 a[4], bh[4], bl[4];
            #pragma unroll
            for (int mi = 0; mi < 4; mi++) {
                int r = wm * 64 + mi * 16 + rA;
                int off = r * 64 + (((kc * 4 + kb) ^ (r & 7)) * 8);
                a[mi] = *(const bf16x8*)(As + off);
            }
            #pragma unroll
            for (int ni = 0; ni < 4; ni++) {
                int r = wn * 64 + ni * 16 + rA;
                int off = r * 64 + (((kc * 4 + kb) ^ (r & 7)) * 8);
                bh[ni] = *(const bf16x8*)(BsH + off);
                bl[ni] = *(const bf16x8*)(BsL + off);
            }
            #pragma unroll
            for (int mi = 0; mi < 4; mi++)
                #pragma unroll
                for (int ni = 0; ni < 4; ni++) {
                    acc[mi][ni] = __builtin_amdgcn_mfma_f32_16x16x32_bf16(a[mi], bh[ni], acc[mi][ni], 0, 0, 0);
                    acc[mi][ni] = __builtin_amdgcn_mfma_f32_16x16x32_bf16(a[mi], bl[ni], acc[mi][ni], 0, 0, 0);
                }
        }
        __syncthreads();
    }

    #pragma unroll
    for (int ni = 0; ni < 4; ni++) {
        int col = bn + wn * 64 + ni * 16 + rA;
        float bv = (EPI == 0) ? bias[col] : 0.f;
        #pragma unroll
        for (int mi = 0; mi < 4; mi++) {
            #pragma unroll
            for (int j = 0; j < 4; j++) {
                int row = bm + wm * 64 + mi * 16 + kb * 4 + j;
                if (row < M) {
                    float v = acc[mi][ni][j];
                    if (EPI == 0) {
                        v = fmaxf(v + bv, 0.f);
                        Obf[(size_t)row * N + col] = (unsigned short)f2bf(v);
                    } else {
                        if (col < 128) Obf[(size_t)row * 128 + col] = (unsigned short)f2bf(v);
                        else           Of[(size_t)row * 128 + (col - 128)] = v;
                    }
                }
            }
        }
    }
}

// ---------------------------------------------------------------------------
// f32 vector GEMM (N=80 merged gat2/res2) + bf16 shadow of cols<40.
// ---------------------------------------------------------------------------
__global__ __launch_bounds__(256) void gemm_bias(const float* __restrict__ A,
                                                 const float* __restrict__ B,
                                                 const float* __restrict__ bias,
                                                 float* __restrict__ C,
                                                 unsigned short* __restrict__ Cbf,
                                                 int M, int N, int K) {
    __shared__ float As[16][65];
    __shared__ float Bs[16][64];
    int tid = threadIdx.x;
    int tx = tid & 15, ty = tid >> 4;
    int bm = blockIdx.y * 64, bn = blockIdx.x * 64;
    int arow = tid >> 2, acol = (tid & 3) << 2;
    int brow = tid >> 4, bcol = (tid & 15) << 2;
    bool fullM = (bm + 64 <= M);
    bool fullN = (bn + 64 <= N);
    float acc[4][4] = {{0.f}};

    for (int k0 = 0; k0 < K; k0 += 16) {
        if (fullM) {
            const float4 av = *(const float4*)(A + (size_t)(bm + arow) * K + (k0 + acol));
            As[acol + 0][arow] = av.x; As[acol + 1][arow] = av.y;
            As[acol + 2][arow] = av.z; As[acol + 3][arow] = av.w;
        } else {
            int r = bm + arow;
            #pragma unroll
            for (int i = 0; i < 4; i++)
                As[acol + i][arow] = (r < M) ? A[(size_t)r * K + k0 + acol + i] : 0.f;
        }
        if (fullN) {
            *(float4*)(&Bs[brow][bcol]) = *(const float4*)(B + (size_t)(k0 + brow) * N + (bn + bcol));
        } else {
            #pragma unroll
            for (int i = 0; i < 4; i++) {
                int c = bn + bcol + i;
                Bs[brow][bcol + i] = (c < N) ? B[(size_t)(k0 + brow) * N + c] : 0.f;
            }
        }
        __syncthreads();
        #pragma unroll
        for (int kk = 0; kk < 16; kk++) {
            float a[4], b[4];
            #pragma unroll
            for (int i = 0; i < 4; i++) a[i] = As[kk][ty * 4 + i];
            #pragma unroll
            for (int j = 0; j < 4; j++) b[j] = Bs[kk][tx * 4 + j];
            #pragma unroll
            for (int i = 0; i < 4; i++)
                #pragma unroll
                for (int j = 0; j < 4; j++) acc[i][j] += a[i] * b[j];
        }
        __syncthreads();
    }

    #pragma unroll
    for (int i = 0; i < 4; i++) {
        int r = bm + ty * 4 + i;
        if (r < M) {
            #pragma unroll
            for (int j = 0; j < 4; j++) {
                int c = bn + tx * 4 + j;
                if (c < N) {
                    float v = acc[i][j] + (bias ? bias[c] : 0.f);
                    C[(size_t)r * N + c] = v;
                    if (Cbf && c < OUTC)
                        Cbf[(size_t)r * OUTC + c] = (unsigned short)f2bf(v);
                }
            }
        }
    }
}

// ---------------------------------------------------------------------------
// Fused weight prep: w1T, w2T, wc1 (hi/lo splits, transposed) + wc2/cb2 (f32)
// ---------------------------------------------------------------------------
__global__ void wprep(const float* __restrict__ ae_w1, const float* __restrict__ ae_w2,
                      const float* __restrict__ g1w, const float* __restrict__ r1w,
                      const float* __restrict__ g2w, const float* __restrict__ r2w,
                      const float* __restrict__ r2b,
                      short* __restrict__ w1Thi, short* __restrict__ w1Tlo,
                      short* __restrict__ w2Thi, short* __restrict__ w2Tlo,
                      short* __restrict__ wc1hi, short* __restrict__ wc1lo,
                      float* __restrict__ wc2, float* __restrict__ cb2) {
    int gid = blockIdx.x * blockDim.x + threadIdx.x;
    if (gid < 131072) {                       // w1T [256 n][512 k]
        int n = gid >> 9, k = gid & 511;
        float v = ae_w1[(size_t)k * 256 + n];
        short hh = f2bf(v);
        w1Thi[gid] = hh; w1Tlo[gid] = f2bf(v - bf2f(hh));
        return;
    }
    gid -= 131072;
    if (gid < 65536) {                        // w2T [256 n][256 k]
        int n = gid >> 8, k = gid & 255;
        float v = ae_w2[(size_t)k * 256 + n];
        short hh = f2bf(v);
        w2Thi[gid] = hh; w2Tlo[gid] = f2bf(v - bf2f(hh));
        return;
    }
    gid -= 65536;
    if (gid < 65536) {                        // wc1 [256 n][256 k]
        int n = gid >> 8, k = gid & 255;
        float v = (n < 128) ? g1w[(size_t)k * 128 + n] : r1w[(size_t)k * 128 + (n - 128)];
        short hh = f2bf(v);
        wc1hi[gid] = hh; wc1lo[gid] = f2bf(v - bf2f(hh));
        return;
    }
    gid -= 65536;
    if (gid < 128 * 80) {                     // wc2 [128 k][80 n]
        int k = gid / 80, n = gid - k * 80;
        wc2[gid] = (n < 40) ? g2w[k * 40 + n] : r2w[k * 40 + (n - 40)];
        return;
    }
    gid -= 128 * 80;
    if (gid < 80) cb2[gid] = (gid < 40) ? 0.f : r2b[gid - 40];
}

// ---------------------------------------------------------------------------
// CSR build (csr + dstslot)
// ---------------------------------------------------------------------------
__global__ void count_deg(const int* __restrict__ dstA, int E, int* __restrict__ deg) {
    int e = blockIdx.x * blockDim.x + threadIdx.x;
    if (e < E) atomicAdd(&deg[dstA[e]], 1);
}

__global__ void scan_part(const int* __restrict__ deg, int N, int* __restrict__ part) {
    __shared__ int s[256];
    int b = blockIdx.x, t = threadIdx.x;
    int i0 = b * 1024 + t * 4;
    int sum = 0;
    #pragma unroll
    for (int j = 0; j < 4; j++) { int i = i0 + j; if (i < N) sum += deg[i] + 1; }
    s[t] = sum; __syncthreads();
    for (int o = 128; o; o >>= 1) { if (t < o) s[t] += s[t + o]; __syncthreads(); }
    if (t == 0) part[b] = s[0];
}

__global__ void scan_base(int* __restrict__ part, int nb, int* __restrict__ offs) {
    int t = threadIdx.x;
    int v = (t < nb) ? part[t] : 0;
    int v0 = v;
    for (int o = 1; o < 64; o <<= 1) {
        int u = __shfl_up(v, o, 64);
        if (t >= o) v += u;
    }
    if (t < nb) part[t] = v - v0;   // exclusive
    if (t == 0) offs[0] = 0;
}

__global__ void scan_final(const int* __restrict__ deg, int N, const int* __restrict__ part,
                           int* __restrict__ offs, int* __restrict__ cur) {
    __shared__ int s[256];
    int b = blockIdx.x, t = threadIdx.x;
    int i0 = b * 1024 + t * 4;
    int v[4]; int sum = 0;
    #pragma unroll
    for (int j = 0; j < 4; j++) { int i = i0 + j; v[j] = (i < N) ? deg[i] + 1 : 0; sum += v[j]; }
    s[t] = sum; __syncthreads();
    for (int o = 1; o < 256; o <<= 1) {
        int add = (t >= o) ? s[t - o] : 0;
        __syncthreads();
        s[t] += add;
        __syncthreads();
    }
    int excl = s[t] - sum + part[b];
    #pragma unroll
    for (int j = 0; j < 4; j++) {
        int i = i0 + j;
        if (i < N) { cur[i] = excl; offs[i + 1] = excl + v[j]; excl += v[j]; }
    }
}

__global__ void scatter_k(const int* __restrict__ srcA, const int* __restrict__ dstA,
                          int E, int* __restrict__ cur, int* __restrict__ csr,
                          int* __restrict__ dstslot) {
    int e = blockIdx.x * blockDim.x + threadIdx.x;
    if (e < E) {
        int dn = dstA[e];
        int p = atomicAdd(&cur[dn], 1);
        csr[p] = srcA[e];
        dstslot[p] = dn;
    }
}

__global__ void selfloop_k(const int* __restrict__ offs, int* __restrict__ csr,
                           int* __restrict__ dstslot, int N) {
    int n = blockIdx.x * blockDim.x + threadIdx.x;
    if (n < N) { int p = offs[n + 1] - 1; csr[p] = n; dstslot[p] = n; }
}

// ---------------------------------------------------------------------------
// Attention score vectors
// ---------------------------------------------------------------------------
__global__ void att1(const unsigned short* __restrict__ h1b, const float* __restrict__ atts,
                     const float* __restrict__ attd, float* __restrict__ as1,
                     float* __restrict__ ad1, int N) {
    int idx = blockIdx.x * blockDim.x + threadIdx.x;
    if (idx >= N * HEADS) return;
    int n = idx >> 2, h = idx & 3;
    const unsigned short* row = h1b + (size_t)n * 128 + h * 32;
    float ss = 0.f, dd = 0.f;
    #pragma unroll
    for (int c4 = 0; c4 < 4; c4++) {
        uint4 v = *(const uint4*)(row + c4 * 8);
        float4 ws1 = *(const float4*)(atts + h * 32 + c4 * 8);
        float4 ws2 = *(const float4*)(atts + h * 32 + c4 * 8 + 4);
        float4 wd1 = *(const float4*)(attd + h * 32 + c4 * 8);
        float4 wd2 = *(const float4*)(attd + h * 32 + c4 * 8 + 4);
        float e0 = bfu2f((unsigned short)(v.x & 0xFFFF)), e1 = bfu2f((unsigned short)(v.x >> 16));
        float e2 = bfu2f((unsigned short)(v.y & 0xFFFF)), e3 = bfu2f((unsigned short)(v.y >> 16));
        float e4 = bfu2f((unsigned short)(v.z & 0xFFFF)), e5 = bfu2f((unsigned short)(v.z >> 16));
        float e6 = bfu2f((unsigned short)(v.w & 0xFFFF)), e7 = bfu2f((unsigned short)(v.w >> 16));
        ss += e0*ws1.x + e1*ws1.y + e2*ws1.z + e3*ws1.w + e4*ws2.x + e5*ws2.y + e6*ws2.z + e7*ws2.w;
        dd += e0*wd1.x + e1*wd1.y + e2*wd1.z + e3*wd1.w + e4*wd2.x + e5*wd2.y + e6*wd2.z + e7*wd2.w;
    }
    as1[idx] = ss; ad1[idx] = dd;
}

__global__ void att2(const float* __restrict__ h2r2, const float* __restrict__ atts,
                     const float* __restrict__ attd, float* __restrict__ as2,
                     float* __restrict__ ad2, int N) {
    int n = blockIdx.x * blockDim.x + threadIdx.x;
    if (n >= N) return;
    const float* row = h2r2 + (size_t)n * 80;
    float ss = 0.f, dd = 0.f;
    #pragma unroll
    for (int c = 0; c < OUTC; c += 4) {
        float4 v = *(const float4*)(row + c);
        float4 ws = *(const float4*)(atts + c);
        float4 wd = *(const float4*)(attd + c);
        ss += v.x*ws.x + v.y*ws.y + v.z*ws.z + v.w*ws.w;
        dd += v.x*wd.x + v.y*wd.y + v.z*wd.z + v.w*wd.w;
    }
    as2[n] = ss; ad2[n] = dd;
}

// ---------------------------------------------------------------------------
// maxden1: per-node per-head max + 1/den. ALSO writes the leaky score v into
// va (slot-major, coalesced) so the alpha pass never re-gathers as1.
// ---------------------------------------------------------------------------
__global__ __launch_bounds__(256) void maxden1(const float* __restrict__ as1,
                                               const float* __restrict__ ad1,
                                               const int* __restrict__ offs,
                                               const int* __restrict__ csr,
                                               float* __restrict__ va,
                                               float* __restrict__ m1,
                                               float* __restrict__ invden1, int N) {
    int n = blockIdx.x * 4 + (threadIdx.x >> 6);
    if (n >= N) return;
    int t = threadIdx.x & 63;
    int h = t >> 4, l = t & 15;
    int beg = offs[n], d = offs[n + 1] - beg;
    float adst = ad1[n * 4 + h];
    float mx = -INFINITY;
    for (int j = l; j < d; j += 16) {
        int idx = beg + j;
        int s = csr[idx];
        float v = as1[s * 4 + h] + adst;
        v = v >= 0.f ? v : SLOPE * v;
        va[(size_t)idx * 4 + h] = v;
        mx = fmaxf(mx, v);
    }
    #pragma unroll
    for (int o = 8; o; o >>= 1) mx = fmaxf(mx, __shfl_xor(mx, o, 16));
    float den = 0.f;
    for (int j = l; j < d; j += 16) {
        den += __expf(va[(size_t)(beg + j) * 4 + h] - mx);
    }
    #pragma unroll
    for (int o = 8; o; o >>= 1) den += __shfl_xor(den, o, 16);
    if (l == 0) {
        m1[n * 4 + h] = mx;
        invden1[n * 4 + h] = 1.f / fmaxf(den, 1e-16f);
    }
}

__global__ __launch_bounds__(256) void maxden2(const float* __restrict__ as2,
                                               const float* __restrict__ ad2,
                                               const int* __restrict__ offs,
                                               const int* __restrict__ csr,
                                               float* __restrict__ va,
                                               float* __restrict__ m2,
                                               float* __restrict__ invden2, int N) {
    int n = blockIdx.x * 4 + (threadIdx.x >> 6);
    if (n >= N) return;
    int t = threadIdx.x & 63;
    int beg = offs[n], d = offs[n + 1] - beg;
    float adst = ad2[n];
    float mx = -INFINITY;
    for (int j = t; j < d; j += 64) {
        int idx = beg + j;
        int s = csr[idx];
        float v = as2[s] + adst;
        v = v >= 0.f ? v : SLOPE * v;
        va[idx] = v;
        mx = fmaxf(mx, v);
    }
    #pragma unroll
    for (int o = 32; o; o >>= 1) mx = fmaxf(mx, __shfl_xor(mx, o, 64));
    float den = 0.f;
    for (int j = t; j < d; j += 64) {
        den += __expf(va[beg + j] - mx);
    }
    #pragma unroll
    for (int o = 32; o; o >>= 1) den += __shfl_xor(den, o, 64);
    if (t == 0) {
        m2[n] = mx;
        invden2[n] = 1.f / fmaxf(den, 1e-16f);
    }
}

// ---------------------------------------------------------------------------
// alpha: in-place linear transform a = exp(a - m[dn]) * inv[dn].
// ---------------------------------------------------------------------------
__global__ void alpha1_k(const int* __restrict__ dstslot,
                         const float* __restrict__ m1, const float* __restrict__ invden1,
                         float* __restrict__ a1, int Etot) {
    int gid = blockIdx.x * blockDim.x + threadIdx.x;
    if (gid >= Etot * 4) return;
    int i = gid >> 2, h = gid & 3;
    int dn = dstslot[i];
    a1[gid] = __expf(a1[gid] - m1[dn * 4 + h]) * invden1[dn * 4 + h];
}

__global__ void alpha2_k(const int* __restrict__ dstslot,
                         const float* __restrict__ m2, const float* __restrict__ invden2,
                         float* __restrict__ a2, int Etot) {
    int i = blockIdx.x * blockDim.x + threadIdx.x;
    if (i >= Etot) return;
    int dn = dstslot[i];
    a2[i] = __expf(a2[i] - m2[dn]) * invden2[dn];
}

// ---------------------------------------------------------------------------
// GAT1 aggregation: wave per node; thread t owns ch {2t,2t+1}, head t>>4.
// 4-deep (s,w) prefetch -> 4 independent gathers in flight per iteration.
// ---------------------------------------------------------------------------
__global__ __launch_bounds__(256) void gat1_agg(const unsigned short* __restrict__ h1b,
                                                const float* __restrict__ r1,
                                                const float* __restrict__ a1,
                                                const int* __restrict__ offs,
                                                const int* __restrict__ csr,
                                                const float* __restrict__ gb,
                                                const float* __restrict__ rb,
                                                float* __restrict__ outh, int N) {
    int n = blockIdx.x * 4 + (threadIdx.x >> 6);
    if (n >= N) return;
    int t = threadIdx.x & 63;
    int h = t >> 4;
    int beg = offs[n], d = offs[n + 1] - beg;

    float acc0 = 0.f, acc1 = 0.f;
    int s[4]; float w[4];
    #pragma unroll
    for (int u = 0; u < 4; u++) {
        bool ok = u < d;
        int idx = beg + (ok ? u : 0);
        s[u] = ok ? csr[idx] : 0;
        w[u] = ok ? a1[(size_t)idx * 4 + h] : 0.f;
    }
    for (int j = 0; j < d; j += 4) {
        int cs[4]; float cw[4];
        #pragma unroll
        for (int u = 0; u < 4; u++) { cs[u] = s[u]; cw[u] = w[u]; }
        #pragma unroll
        for (int u = 0; u < 4; u++) {
            int jj = j + 4 + u;
            bool ok = jj < d;
            int idx = beg + (ok ? jj : 0);
            s[u] = ok ? csr[idx] : 0;
            w[u] = ok ? a1[(size_t)idx * 4 + h] : 0.f;
        }
        #pragma unroll
        for (int u = 0; u < 4; u++) {
            ushort2 hv = *(const ushort2*)(h1b + (size_t)cs[u] * 128 + 2 * t);
            acc0 += cw[u] * bfu2f(hv.x);
            acc1 += cw[u] * bfu2f(hv.y);
        }
    }
    float2 rv = *(const float2*)(r1 + (size_t)n * 128 + 2 * t);
    float2 gv = *(const float2*)(gb + 2 * t);
    float2 bv = *(const float2*)(rb + 2 * t);
    float o0 = fmaxf(acc0 + gv.x + bv.x + rv.x, 0.f);
    float o1 = fmaxf(acc1 + gv.y + bv.y + rv.y, 0.f);
    float2 ov = {o0, o1};
    *(float2*)(outh + (size_t)n * 128 + 2 * t) = ov;
}

// ---------------------------------------------------------------------------
// GAT2 aggregation: wave per node; lanes t<20 own ch {2t,2t+1}; 4-deep prefetch.
// ---------------------------------------------------------------------------
__global__ __launch_bounds__(256) void gat2_agg(const unsigned short* __restrict__ h2b,
                                                const float* __restrict__ h2r2,
                                                const float* __restrict__ a2,
                                                const int* __restrict__ offs,
                                                const int* __restrict__ csr,
                                                const float* __restrict__ gb,
                                                float* __restrict__ out, int N) {
    int n = blockIdx.x * 4 + (threadIdx.x >> 6);
    if (n >= N) return;
    int t = threadIdx.x & 63;
    int beg = offs[n], d = offs[n + 1] - beg;

    float acc0 = 0.f, acc1 = 0.f;
    int s[4]; float w[4];
    #pragma unroll
    for (int u = 0; u < 4; u++) {
        bool ok = u < d;
        int idx = beg + (ok ? u : 0);
        s[u] = ok ? csr[idx] : 0;
        w[u] = ok ? a2[idx] : 0.f;
    }
    for (int j = 0; j < d; j += 4) {
        int cs[4]; float cw[4];
        #pragma unroll
        for (int u = 0; u < 4; u++) { cs[u] = s[u]; cw[u] = w[u]; }
        #pragma unroll
        for (int u = 0; u < 4; u++) {
            int jj = j + 4 + u;
            bool ok = jj < d;
            int idx = beg + (ok ? jj : 0);
            s[u] = ok ? csr[idx] : 0;
            w[u] = ok ? a2[idx] : 0.f;
        }
        if (t < 20) {
            #pragma unroll
            for (int u = 0; u < 4; u++) {
                ushort2 hv = *(const ushort2*)(h2b + (size_t)cs[u] * OUTC + 2 * t);
                acc0 += cw[u] * bfu2f(hv.x);
                acc1 += cw[u] * bfu2f(hv.y);
            }
        }
    }
    if (t < 20) {
        float2 rr = *(const float2*)(h2r2 + (size_t)n * 80 + 40 + 2 * t);
        float2 gv = *(const float2*)(gb + 2 * t);
        float2 ov = {acc0 + gv.x + rr.x, acc1 + gv.y + rr.y};
        *(float2*)(out + (size_t)n * OUTC + 2 * t) = ov;
    }
}

// ---------------------------------------------------------------------------
// Launcher
// ---------------------------------------------------------------------------
extern "C" void kernel_launch(void* const* d_in, const int* in_sizes, int n_in,
                              void* d_out, int out_size, void* d_ws, size_t ws_size,
                              hipStream_t stream) {
    const float* x      = (const float*)d_in[0];
    const int*   ei     = (const int*)d_in[1];
    const float* ae_w1  = (const float*)d_in[2];
    const float* ae_b1  = (const float*)d_in[3];
    const float* ae_w2  = (const float*)d_in[4];
    const float* ae_b2  = (const float*)d_in[5];
    const float* gat1_w = (const float*)d_in[6];
    const float* g1as   = (const float*)d_in[7];
    const float* g1ad   = (const float*)d_in[8];
    const float* g1b    = (const float*)d_in[9];
    const float* gat2_w = (const float*)d_in[10];
    const float* g2as   = (const float*)d_in[11];
    const float* g2ad   = (const float*)d_in[12];
    const float* g2b    = (const float*)d_in[13];
    const float* res1_w = (const float*)d_in[14];
    const float* res1_b = (const float*)d_in[15];
    const float* res2_w = (const float*)d_in[16];
    const float* res2_b = (const float*)d_in[17];
    float* out = (float*)d_out;

    const int Nn = in_sizes[0] / 512;       // 50000 nodes
    const int E  = in_sizes[1] / 2;         // 800000 edges
    const int Etot = E + Nn;

    const int* srcA = ei;
    const int* dstA = ei + E;

    // ---- workspace layout ----
    char* W = (char*)d_ws;
    size_t off = 0;
    auto alloc = [&](size_t bytes) { char* p = W + off; off += (bytes + 255) & ~(size_t)255; return p; };

    // Region1: xb bf16 [Nn,512]; after fc1 reused as hbuf/h2r2/h2bf
    char* reg1 = alloc((size_t)Nn * 512 * 2);
    unsigned short* xb = (unsigned short*)reg1;
    float* hbuf = (float*)reg1;                                  // [Nn,128] f32
    float* h2r2 = (float*)(reg1 + (size_t)Nn * 128 * 4);         // [Nn,80] f32
    unsigned short* h2bf = (unsigned short*)(reg1 + (size_t)Nn * 208 * 4); // [Nn,40]

    // Region2: y1b bf16 [Nn,256]; after fc2 reused as r1 f32 [Nn,128]
    char* reg2 = alloc((size_t)Nn * 256 * 2);
    unsigned short* y1b = (unsigned short*)reg2;
    float* r1 = (float*)reg2;

    unsigned short* xeb = (unsigned short*)alloc((size_t)Nn * 256 * 2);
    unsigned short* h1b = (unsigned short*)alloc((size_t)Nn * 128 * 2);

    short* w1Thi = (short*)alloc(256 * 512 * 2);
    short* w1Tlo = (short*)alloc(256 * 512 * 2);
    short* w2Thi = (short*)alloc(256 * 256 * 2);
    short* w2Tlo = (short*)alloc(256 * 256 * 2);
    short* wc1hi = (short*)alloc(256 * 256 * 2);
    short* wc1lo = (short*)alloc(256 * 256 * 2);
    float* wc2   = (float*)alloc(128 * 80 * 4);
    float* cb2   = (float*)alloc(128 * 4);
    float* as1   = (float*)alloc((size_t)Nn * HEADS * 4);
    float* ad1   = (float*)alloc((size_t)Nn * HEADS * 4);
    float* as2   = (float*)alloc((size_t)Nn * 4);
    float* ad2   = (float*)alloc((size_t)Nn * 4);
    float* m1    = (float*)alloc((size_t)Nn * HEADS * 4);
    float* iv1   = (float*)alloc((size_t)Nn * HEADS * 4);
    float* m2    = (float*)alloc((size_t)Nn * 4);
    float* iv2   = (float*)alloc((size_t)Nn * 4);
    float* a1    = (float*)alloc((size_t)Etot * HEADS * 4);     // 13.6 MB
    float* a2    = (float*)alloc((size_t)Etot * 4);             // 3.4 MB
    int* deg  = (int*)alloc((size_t)Nn * 4);
    int* offs = (int*)alloc((size_t)(Nn + 1) * 4);
    int* cur  = (int*)alloc((size_t)Nn * 4);
    int* part = (int*)alloc(256 * 4);
    int* csr  = (int*)alloc((size_t)Etot * 4);
    int* dsl  = (int*)alloc((size_t)Etot * 4);

    // ---- weight prep (fused) ----
    {
        int total = 131072 + 65536 + 65536 + 128 * 80 + 80;
        wprep<<<(total + 255) / 256, 256, 0, stream>>>(
            ae_w1, ae_w2, gat1_w, res1_w, gat2_w, res2_w, res2_b,
            w1Thi, w1Tlo, w2Thi, w2Tlo, wc1hi, wc1lo, wc2, cb2);
    }

    // ---- CSR build ----
    hipMemsetAsync(deg, 0, (size_t)Nn * sizeof(int), stream);
    count_deg<<<(E + 255) / 256, 256, 0, stream>>>(dstA, E, deg);
    int nb = (Nn + 1023) / 1024;
    scan_part<<<nb, 256, 0, stream>>>(deg, Nn, part);
    scan_base<<<1, 64, 0, stream>>>(part, nb, offs);
    scan_final<<<nb, 256, 0, stream>>>(deg, Nn, part, offs, cur);
    scatter_k<<<(E + 255) / 256, 256, 0, stream>>>(srcA, dstA, E, cur, csr, dsl);
    selfloop_k<<<(Nn + 255) / 256, 256, 0, stream>>>(offs, csr, dsl, Nn);

    // ---- x -> bf16 ----
    long xtotal = (long)Nn * 512;
    x2bf<<<(int)((xtotal / 8 + 255) / 256), 256, 0, stream>>>(x, (unsigned int*)xb, xtotal);

    const int gy = (Nn + 127) / 128;   // 391

    // ---- fc1 / fc2 / gatres1 ----
    gemm2<0><<<dim3(2, gy), 256, 0, stream>>>(
        (const short*)xb, w1Thi, w1Tlo, ae_b1, y1b, nullptr, Nn, 256, 512);
    gemm2<0><<<dim3(2, gy), 256, 0, stream>>>(
        (const short*)y1b, w2Thi, w2Tlo, ae_b2, xeb, nullptr, Nn, 256, 256);
    gemm2<1><<<dim3(2, gy), 256, 0, stream>>>(
        (const short*)xeb, wc1hi, wc1lo, nullptr, h1b, r1, Nn, 256, 256);

    // ---- layer-1 attention path ----
    att1<<<(Nn * HEADS + 255) / 256, 256, 0, stream>>>(h1b, g1as, g1ad, as1, ad1, Nn);
    maxden1<<<(Nn + 3) / 4, 256, 0, stream>>>(as1, ad1, offs, csr, a1, m1, iv1, Nn);
    alpha1_k<<<(Etot * 4 + 255) / 256, 256, 0, stream>>>(dsl, m1, iv1, a1, Etot);
    gat1_agg<<<(Nn + 3) / 4, 256, 0, stream>>>(h1b, r1, a1, offs, csr, g1b, res1_b, hbuf, Nn);

    // ---- gatres2 (f32) ----
    gemm_bias<<<dim3(2, (Nn + 63) / 64), 256, 0, stream>>>(hbuf, wc2, cb2, h2r2, h2bf, Nn, 80, 128);

    // ---- layer-2 attention path ----
    att2<<<(Nn + 255) / 256, 256, 0, stream>>>(h2r2, g2as, g2ad, as2, ad2, Nn);
    maxden2<<<(Nn + 3) / 4, 256, 0, stream>>>(as2, ad2, offs, csr, a2, m2, iv2, Nn);
    alpha2_k<<<(Etot + 255) / 256, 256, 0, stream>>>(dsl, m2, iv2, a2, Etot);
    gat2_agg<<<(Nn + 3) / 4, 256, 0, stream>>>(h2bf, h2r2, a2, offs, csr, g2b, out, Nn);
}

// Round 7
// 395.094 us; speedup vs baseline: 1.3600x; 1.0539x over previous
//
#include <hip/hip_runtime.h>
#include <hip/hip_bf16.h>
#include <math.h>

#define HEADS 4
#define OUTC 40
#define SLOPE 0.2f

typedef __attribute__((ext_vector_type(8))) short bf16x8;
typedef __attribute__((ext_vector_type(4))) float f32x4;

__device__ __forceinline__ short f2bf(float f) {
    unsigned u = __float_as_uint(f);
    unsigned r = (u + 0x7FFFu + ((u >> 16) & 1u)) >> 16;
    return (short)r;
}
__device__ __forceinline__ float bf2f(short s) {
    return __uint_as_float(((unsigned)(unsigned short)s) << 16);
}
__device__ __forceinline__ float bfu2f(unsigned short s) {
    return __uint_as_float(((unsigned)s) << 16);
}

typedef const __attribute__((address_space(1))) unsigned int gu32;
typedef __attribute__((address_space(3))) unsigned int lu32;
__device__ __forceinline__ void gll16(const void* src, void* lds) {
    __builtin_amdgcn_global_load_lds((gu32*)src, (lu32*)lds, 16, 0, 0);
}

// ---------------------------------------------------------------------------
// x -> bf16 conversion (pure BW pass)
// ---------------------------------------------------------------------------
__global__ void x2bf(const float* __restrict__ x, unsigned int* __restrict__ xb,
                     long total) {
    long i = ((long)blockIdx.x * blockDim.x + threadIdx.x) * 8;
    if (i >= total) return;
    float4 a = *(const float4*)(x + i);
    float4 b = *(const float4*)(x + i + 4);
    uint4 o;
    o.x = (unsigned short)f2bf(a.x) | ((unsigned)(unsigned short)f2bf(a.y) << 16);
    o.y = (unsigned short)f2bf(a.z) | ((unsigned)(unsigned short)f2bf(a.w) << 16);
    o.z = (unsigned short)f2bf(b.x) | ((unsigned)(unsigned short)f2bf(b.y) << 16);
    o.w = (unsigned short)f2bf(b.z) | ((unsigned)(unsigned short)f2bf(b.w) << 16);
    *(uint4*)(xb + i / 2) = o;
}

// ---------------------------------------------------------------------------
// Pure-bf16 MFMA GEMM: C[M,N] = A[M,K] @ B[K,N]. A bf16 plane; B bf16
// TRANSPOSED plane [N][K]. BM=BN=128, BK=64, 4 waves, 32 KB LDS.
// EPI=0: relu(acc+bias) -> bf16. EPI=1: cols<128 -> bf16 Obf; cols>=128 -> f32 Of.
// ---------------------------------------------------------------------------
template<int EPI>
__global__ __launch_bounds__(256) void gemm2(
    const short* __restrict__ A,
    const short* __restrict__ B,
    const float* __restrict__ bias,
    unsigned short* __restrict__ Obf, float* __restrict__ Of,
    int M, int N, int K)
{
    __shared__ short smem[16384];          // 32 KB
    short* As = smem;                      // 128x64 bf16 (16 KB)
    short* Bs = smem + 8192;

    const int tid = threadIdx.x;
    const int wid = tid >> 6, lane = tid & 63;
    const int bm = blockIdx.y * 128, bn = blockIdx.x * 128;
    const int wm = wid >> 1, wn = wid & 1;
    const int rA = lane & 15, kb = lane >> 4;

    f32x4 acc[4][4];
    #pragma unroll
    for (int i = 0; i < 4; i++)
        #pragma unroll
        for (int j = 0; j < 4; j++)
            acc[i][j] = (f32x4){0.f, 0.f, 0.f, 0.f};

    const int KT = K >> 6;
    for (int kt = 0; kt < KT; kt++) {
        const int k0 = kt << 6;
        #pragma unroll
        for (int it = 0; it < 4; it++) {
            int g = it * 256 + tid;
            int row = g >> 3, gr = g & 7;
            int gsrc = gr ^ (row & 7);
            int grow = bm + row; if (grow > M - 1) grow = M - 1;
            gll16(A + (size_t)grow * K + k0 + gsrc * 8,
                  As + (it * 256 + wid * 64) * 8);
        }
        #pragma unroll
        for (int it = 0; it < 4; it++) {
            int g = it * 256 + tid;
            int row = g >> 3, gr = g & 7;
            int gsrc = gr ^ (row & 7);
            gll16(B + (size_t)(bn + row) * K + k0 + gsrc * 8,
                  Bs + (it * 256 + wid * 64) * 8);
        }
        __syncthreads();
        #pragma unroll
        for (int kc = 0; kc < 2; kc++) {
            bf16x8 a[4], b[4];
            #pragma unroll
            for (int mi = 0; mi < 4; mi++) {
                int r = wm * 64 + mi * 16 + rA;
                int off = r * 64 + (((kc * 4 + kb) ^ (r & 7)) * 8);
                a[mi] = *(const bf16x8*)(As + off);
            }
            #pragma unroll
            for (int ni = 0; ni < 4; ni++) {
                int r = wn * 64 + ni * 16 + rA;
                int off = r * 64 + (((kc * 4 + kb) ^ (r & 7)) * 8);
                b[ni] = *(const bf16x8*)(Bs + off);
            }
            #pragma unroll
            for (int mi = 0; mi < 4; mi++)
                #pragma unroll
                for (int ni = 0; ni < 4; ni++)
                    acc[mi][ni] = __builtin_amdgcn_mfma_f32_16x16x32_bf16(a[mi], b[ni], acc[mi][ni], 0, 0, 0);
        }
        __syncthreads();
    }

    #pragma unroll
    for (int ni = 0; ni < 4; ni++) {
        int col = bn + wn * 64 + ni * 16 + rA;
        float bv = (EPI == 0) ? bias[col] : 0.f;
        #pragma unroll
        for (int mi = 0; mi < 4; mi++) {
            #pragma unroll
            for (int j = 0; j < 4; j++) {
                int row = bm + wm * 64 + mi * 16 + kb * 4 + j;
                if (row < M) {
                    float v = acc[mi][ni][j];
                    if (EPI == 0) {
                        v = fmaxf(v + bv, 0.f);
                        Obf[(size_t)row * N + col] = (unsigned short)f2bf(v);
                    } else {
                        if (col < 128) Obf[(size_t)row * 128 + col] = (unsigned short)f2bf(v);
                        else           Of[(size_t)row * 128 + (col - 128)] = v;
                    }
                }
            }
        }
    }
}

// ---------------------------------------------------------------------------
// f32 vector GEMM (N=80 merged gat2/res2) + bf16 shadow of cols<40.
// ---------------------------------------------------------------------------
__global__ __launch_bounds__(256) void gemm_bias(const float* __restrict__ A,
                                                 const float* __restrict__ B,
                                                 const float* __restrict__ bias,
                                                 float* __restrict__ C,
                                                 unsigned short* __restrict__ Cbf,
                                                 int M, int N, int K) {
    __shared__ float As[16][65];
    __shared__ float Bs[16][64];
    int tid = threadIdx.x;
    int tx = tid & 15, ty = tid >> 4;
    int bm = blockIdx.y * 64, bn = blockIdx.x * 64;
    int arow = tid >> 2, acol = (tid & 3) << 2;
    int brow = tid >> 4, bcol = (tid & 15) << 2;
    bool fullM = (bm + 64 <= M);
    bool fullN = (bn + 64 <= N);
    float acc[4][4] = {{0.f}};

    for (int k0 = 0; k0 < K; k0 += 16) {
        if (fullM) {
            const float4 av = *(const float4*)(A + (size_t)(bm + arow) * K + (k0 + acol));
            As[acol + 0][arow] = av.x; As[acol + 1][arow] = av.y;
            As[acol + 2][arow] = av.z; As[acol + 3][arow] = av.w;
        } else {
            int r = bm + arow;
            #pragma unroll
            for (int i = 0; i < 4; i++)
                As[acol + i][arow] = (r < M) ? A[(size_t)r * K + k0 + acol + i] : 0.f;
        }
        if (fullN) {
            *(float4*)(&Bs[brow][bcol]) = *(const float4*)(B + (size_t)(k0 + brow) * N + (bn + bcol));
        } else {
            #pragma unroll
            for (int i = 0; i < 4; i++) {
                int c = bn + bcol + i;
                Bs[brow][bcol + i] = (c < N) ? B[(size_t)(k0 + brow) * N + c] : 0.f;
            }
        }
        __syncthreads();
        #pragma unroll
        for (int kk = 0; kk < 16; kk++) {
            float a[4], b[4];
            #pragma unroll
            for (int i = 0; i < 4; i++) a[i] = As[kk][ty * 4 + i];
            #pragma unroll
            for (int j = 0; j < 4; j++) b[j] = Bs[kk][tx * 4 + j];
            #pragma unroll
            for (int i = 0; i < 4; i++)
                #pragma unroll
                for (int j = 0; j < 4; j++) acc[i][j] += a[i] * b[j];
        }
        __syncthreads();
    }

    #pragma unroll
    for (int i = 0; i < 4; i++) {
        int r = bm + ty * 4 + i;
        if (r < M) {
            #pragma unroll
            for (int j = 0; j < 4; j++) {
                int c = bn + tx * 4 + j;
                if (c < N) {
                    float v = acc[i][j] + (bias ? bias[c] : 0.f);
                    C[(size_t)r * N + c] = v;
                    if (Cbf && c < OUTC)
                        Cbf[(size_t)r * OUTC + c] = (unsigned short)f2bf(v);
                }
            }
        }
    }
}

// ---------------------------------------------------------------------------
// Fused weight prep (bf16 transposed planes, no lo) + wc2/cb2 (f32)
// ---------------------------------------------------------------------------
__global__ void wprep(const float* __restrict__ ae_w1, const float* __restrict__ ae_w2,
                      const float* __restrict__ g1w, const float* __restrict__ r1w,
                      const float* __restrict__ g2w, const float* __restrict__ r2w,
                      const float* __restrict__ r2b,
                      short* __restrict__ w1T, short* __restrict__ w2T,
                      short* __restrict__ wc1,
                      float* __restrict__ wc2, float* __restrict__ cb2) {
    int gid = blockIdx.x * blockDim.x + threadIdx.x;
    if (gid < 131072) {                       // w1T [256 n][512 k]
        int n = gid >> 9, k = gid & 511;
        w1T[gid] = f2bf(ae_w1[(size_t)k * 256 + n]);
        return;
    }
    gid -= 131072;
    if (gid < 65536) {                        // w2T [256 n][256 k]
        int n = gid >> 8, k = gid & 255;
        w2T[gid] = f2bf(ae_w2[(size_t)k * 256 + n]);
        return;
    }
    gid -= 65536;
    if (gid < 65536) {                        // wc1 [256 n][256 k]
        int n = gid >> 8, k = gid & 255;
        float v = (n < 128) ? g1w[(size_t)k * 128 + n] : r1w[(size_t)k * 128 + (n - 128)];
        wc1[gid] = f2bf(v);
        return;
    }
    gid -= 65536;
    if (gid < 128 * 80) {                     // wc2 [128 k][80 n]
        int k = gid / 80, n = gid - k * 80;
        wc2[gid] = (n < 40) ? g2w[k * 40 + n] : r2w[k * 40 + (n - 40)];
        return;
    }
    gid -= 128 * 80;
    if (gid < 80) cb2[gid] = (gid < 40) ? 0.f : r2b[gid - 40];
}

// ---------------------------------------------------------------------------
// CSR build
// ---------------------------------------------------------------------------
__global__ void count_deg(const int* __restrict__ dstA, int E, int* __restrict__ deg) {
    int e = blockIdx.x * blockDim.x + threadIdx.x;
    if (e < E) atomicAdd(&deg[dstA[e]], 1);
}

__global__ void scan_part(const int* __restrict__ deg, int N, int* __restrict__ part) {
    __shared__ int s[256];
    int b = blockIdx.x, t = threadIdx.x;
    int i0 = b * 1024 + t * 4;
    int sum = 0;
    #pragma unroll
    for (int j = 0; j < 4; j++) { int i = i0 + j; if (i < N) sum += deg[i] + 1; }
    s[t] = sum; __syncthreads();
    for (int o = 128; o; o >>= 1) { if (t < o) s[t] += s[t + o]; __syncthreads(); }
    if (t == 0) part[b] = s[0];
}

__global__ void scan_base(int* __restrict__ part, int nb, int* __restrict__ offs) {
    int t = threadIdx.x;
    int v = (t < nb) ? part[t] : 0;
    int v0 = v;
    for (int o = 1; o < 64; o <<= 1) {
        int u = __shfl_up(v, o, 64);
        if (t >= o) v += u;
    }
    if (t < nb) part[t] = v - v0;   // exclusive
    if (t == 0) offs[0] = 0;
}

__global__ void scan_final(const int* __restrict__ deg, int N, const int* __restrict__ part,
                           int* __restrict__ offs, int* __restrict__ cur) {
    __shared__ int s[256];
    int b = blockIdx.x, t = threadIdx.x;
    int i0 = b * 1024 + t * 4;
    int v[4]; int sum = 0;
    #pragma unroll
    for (int j = 0; j < 4; j++) { int i = i0 + j; v[j] = (i < N) ? deg[i] + 1 : 0; sum += v[j]; }
    s[t] = sum; __syncthreads();
    for (int o = 1; o < 256; o <<= 1) {
        int add = (t >= o) ? s[t - o] : 0;
        __syncthreads();
        s[t] += add;
        __syncthreads();
    }
    int excl = s[t] - sum + part[b];
    #pragma unroll
    for (int j = 0; j < 4; j++) {
        int i = i0 + j;
        if (i < N) { cur[i] = excl; offs[i + 1] = excl + v[j]; excl += v[j]; }
    }
}

__global__ void scatter_k(const int* __restrict__ srcA, const int* __restrict__ dstA,
                          int E, int* __restrict__ cur, int* __restrict__ csr) {
    int e = blockIdx.x * blockDim.x + threadIdx.x;
    if (e < E) {
        int p = atomicAdd(&cur[dstA[e]], 1);
        csr[p] = srcA[e];
    }
}

__global__ void selfloop_k(const int* __restrict__ offs, int* __restrict__ csr, int N) {
    int n = blockIdx.x * blockDim.x + threadIdx.x;
    if (n < N) csr[offs[n + 1] - 1] = n;
}

// ---------------------------------------------------------------------------
// Attention score vectors
// ---------------------------------------------------------------------------
__global__ void att1(const unsigned short* __restrict__ h1b, const float* __restrict__ atts,
                     const float* __restrict__ attd, float* __restrict__ as1,
                     float* __restrict__ ad1, int N) {
    int idx = blockIdx.x * blockDim.x + threadIdx.x;
    if (idx >= N * HEADS) return;
    int n = idx >> 2, h = idx & 3;
    const unsigned short* row = h1b + (size_t)n * 128 + h * 32;
    float ss = 0.f, dd = 0.f;
    #pragma unroll
    for (int c4 = 0; c4 < 4; c4++) {
        uint4 v = *(const uint4*)(row + c4 * 8);
        float4 ws1 = *(const float4*)(atts + h * 32 + c4 * 8);
        float4 ws2 = *(const float4*)(atts + h * 32 + c4 * 8 + 4);
        float4 wd1 = *(const float4*)(attd + h * 32 + c4 * 8);
        float4 wd2 = *(const float4*)(attd + h * 32 + c4 * 8 + 4);
        float e0 = bfu2f((unsigned short)(v.x & 0xFFFF)), e1 = bfu2f((unsigned short)(v.x >> 16));
        float e2 = bfu2f((unsigned short)(v.y & 0xFFFF)), e3 = bfu2f((unsigned short)(v.y >> 16));
        float e4 = bfu2f((unsigned short)(v.z & 0xFFFF)), e5 = bfu2f((unsigned short)(v.z >> 16));
        float e6 = bfu2f((unsigned short)(v.w & 0xFFFF)), e7 = bfu2f((unsigned short)(v.w >> 16));
        ss += e0*ws1.x + e1*ws1.y + e2*ws1.z + e3*ws1.w + e4*ws2.x + e5*ws2.y + e6*ws2.z + e7*ws2.w;
        dd += e0*wd1.x + e1*wd1.y + e2*wd1.z + e3*wd1.w + e4*wd2.x + e5*wd2.y + e6*wd2.z + e7*wd2.w;
    }
    as1[idx] = ss; ad1[idx] = dd;
}

__global__ void att2(const float* __restrict__ h2r2, const float* __restrict__ atts,
                     const float* __restrict__ attd, float* __restrict__ as2,
                     float* __restrict__ ad2, int N) {
    int n = blockIdx.x * blockDim.x + threadIdx.x;
    if (n >= N) return;
    const float* row = h2r2 + (size_t)n * 80;
    float ss = 0.f, dd = 0.f;
    #pragma unroll
    for (int c = 0; c < OUTC; c += 4) {
        float4 v = *(const float4*)(row + c);
        float4 ws = *(const float4*)(atts + c);
        float4 wd = *(const float4*)(attd + c);
        ss += v.x*ws.x + v.y*ws.y + v.z*ws.z + v.w*ws.w;
        dd += v.x*wd.x + v.y*wd.y + v.z*wd.z + v.w*wd.w;
    }
    as2[n] = ss; ad2[n] = dd;
}

// ---------------------------------------------------------------------------
// maxden1: per-node per-head max + 1/den. Writes the leaky score v into va
// (slot-major, coalesced) so downstream passes never re-gather as1.
// ---------------------------------------------------------------------------
__global__ __launch_bounds__(256) void maxden1(const float* __restrict__ as1,
                                               const float* __restrict__ ad1,
                                               const int* __restrict__ offs,
                                               const int* __restrict__ csr,
                                               float* __restrict__ va,
                                               float* __restrict__ m1,
                                               float* __restrict__ invden1, int N) {
    int n = blockIdx.x * 4 + (threadIdx.x >> 6);
    if (n >= N) return;
    int t = threadIdx.x & 63;
    int h = t >> 4, l = t & 15;
    int beg = offs[n], d = offs[n + 1] - beg;
    float adst = ad1[n * 4 + h];
    float mx = -INFINITY;
    for (int j = l; j < d; j += 16) {
        int idx = beg + j;
        int s = csr[idx];
        float v = as1[s * 4 + h] + adst;
        v = v >= 0.f ? v : SLOPE * v;
        va[(size_t)idx * 4 + h] = v;
        mx = fmaxf(mx, v);
    }
    #pragma unroll
    for (int o = 8; o; o >>= 1) mx = fmaxf(mx, __shfl_xor(mx, o, 16));
    float den = 0.f;
    for (int j = l; j < d; j += 16) {
        den += __expf(va[(size_t)(beg + j) * 4 + h] - mx);
    }
    #pragma unroll
    for (int o = 8; o; o >>= 1) den += __shfl_xor(den, o, 16);
    if (l == 0) {
        m1[n * 4 + h] = mx;
        invden1[n * 4 + h] = 1.f / fmaxf(den, 1e-16f);
    }
}

__global__ __launch_bounds__(256) void maxden2(const float* __restrict__ as2,
                                               const float* __restrict__ ad2,
                                               const int* __restrict__ offs,
                                               const int* __restrict__ csr,
                                               float* __restrict__ va,
                                               float* __restrict__ m2,
                                               float* __restrict__ invden2, int N) {
    int n = blockIdx.x * 4 + (threadIdx.x >> 6);
    if (n >= N) return;
    int t = threadIdx.x & 63;
    int beg = offs[n], d = offs[n + 1] - beg;
    float adst = ad2[n];
    float mx = -INFINITY;
    for (int j = t; j < d; j += 64) {
        int idx = beg + j;
        int s = csr[idx];
        float v = as2[s] + adst;
        v = v >= 0.f ? v : SLOPE * v;
        va[idx] = v;
        mx = fmaxf(mx, v);
    }
    #pragma unroll
    for (int o = 32; o; o >>= 1) mx = fmaxf(mx, __shfl_xor(mx, o, 64));
    float den = 0.f;
    for (int j = t; j < d; j += 64) {
        den += __expf(va[beg + j] - mx);
    }
    #pragma unroll
    for (int o = 32; o; o >>= 1) den += __shfl_xor(den, o, 64);
    if (t == 0) {
        m2[n] = mx;
        invden2[n] = 1.f / fmaxf(den, 1e-16f);
    }
}

// ---------------------------------------------------------------------------
// GAT1 aggregation: wave per node; thread t owns ch {2t,2t+1}, head t>>4.
// Reads raw scores va; exp(v - m[n,h]) inline (m, inv are wave-uniform per
// head); 4-deep (s,v) prefetch -> 4 independent gathers in flight.
// ---------------------------------------------------------------------------
__global__ __launch_bounds__(256) void gat1_agg(const unsigned short* __restrict__ h1b,
                                                const float* __restrict__ r1,
                                                const float* __restrict__ va,
                                                const float* __restrict__ m1,
                                                const float* __restrict__ iv1,
                                                const int* __restrict__ offs,
                                                const int* __restrict__ csr,
                                                const float* __restrict__ gb,
                                                const float* __restrict__ rb,
                                                float* __restrict__ outh, int N) {
    int n = blockIdx.x * 4 + (threadIdx.x >> 6);
    if (n >= N) return;
    int t = threadIdx.x & 63;
    int h = t >> 4;
    int beg = offs[n], d = offs[n + 1] - beg;
    float m = m1[n * 4 + h];
    float iv = iv1[n * 4 + h];

    float acc0 = 0.f, acc1 = 0.f;
    int s[4]; float w[4];
    #pragma unroll
    for (int u = 0; u < 4; u++) {
        bool ok = u < d;
        int idx = beg + (ok ? u : 0);
        s[u] = ok ? csr[idx] : 0;
        w[u] = ok ? va[(size_t)idx * 4 + h] : -1e30f;
    }
    for (int j = 0; j < d; j += 4) {
        int cs[4]; float cw[4];
        #pragma unroll
        for (int u = 0; u < 4; u++) { cs[u] = s[u]; cw[u] = __expf(w[u] - m); }
        #pragma unroll
        for (int u = 0; u < 4; u++) {
            int jj = j + 4 + u;
            bool ok = jj < d;
            int idx = beg + (ok ? jj : 0);
            s[u] = ok ? csr[idx] : 0;
            w[u] = ok ? va[(size_t)idx * 4 + h] : -1e30f;
        }
        #pragma unroll
        for (int u = 0; u < 4; u++) {
            ushort2 hv = *(const ushort2*)(h1b + (size_t)cs[u] * 128 + 2 * t);
            acc0 += cw[u] * bfu2f(hv.x);
            acc1 += cw[u] * bfu2f(hv.y);
        }
    }
    acc0 *= iv; acc1 *= iv;
    float2 rv = *(const float2*)(r1 + (size_t)n * 128 + 2 * t);
    float2 gv = *(const float2*)(gb + 2 * t);
    float2 bv = *(const float2*)(rb + 2 * t);
    float o0 = fmaxf(acc0 + gv.x + bv.x + rv.x, 0.f);
    float o1 = fmaxf(acc1 + gv.y + bv.y + rv.y, 0.f);
    float2 ov = {o0, o1};
    *(float2*)(outh + (size_t)n * 128 + 2 * t) = ov;
}

// ---------------------------------------------------------------------------
// GAT2 aggregation: wave per node; lanes t<20 own ch {2t,2t+1}; inline exp.
// ---------------------------------------------------------------------------
__global__ __launch_bounds__(256) void gat2_agg(const unsigned short* __restrict__ h2b,
                                                const float* __restrict__ h2r2,
                                                const float* __restrict__ va,
                                                const float* __restrict__ m2,
                                                const float* __restrict__ iv2,
                                                const int* __restrict__ offs,
                                                const int* __restrict__ csr,
                                                const float* __restrict__ gb,
                                                float* __restrict__ out, int N) {
    int n = blockIdx.x * 4 + (threadIdx.x >> 6);
    if (n >= N) return;
    int t = threadIdx.x & 63;
    int beg = offs[n], d = offs[n + 1] - beg;
    float m = m2[n];
    float iv = iv2[n];

    float acc0 = 0.f, acc1 = 0.f;
    int s[4]; float w[4];
    #pragma unroll
    for (int u = 0; u < 4; u++) {
        bool ok = u < d;
        int idx = beg + (ok ? u : 0);
        s[u] = ok ? csr[idx] : 0;
        w[u] = ok ? va[idx] : -1e30f;
    }
    for (int j = 0; j < d; j += 4) {
        int cs[4]; float cw[4];
        #pragma unroll
        for (int u = 0; u < 4; u++) { cs[u] = s[u]; cw[u] = __expf(w[u] - m); }
        #pragma unroll
        for (int u = 0; u < 4; u++) {
            int jj = j + 4 + u;
            bool ok = jj < d;
            int idx = beg + (ok ? jj : 0);
            s[u] = ok ? csr[idx] : 0;
            w[u] = ok ? va[idx] : -1e30f;
        }
        if (t < 20) {
            #pragma unroll
            for (int u = 0; u < 4; u++) {
                ushort2 hv = *(const ushort2*)(h2b + (size_t)cs[u] * OUTC + 2 * t);
                acc0 += cw[u] * bfu2f(hv.x);
                acc1 += cw[u] * bfu2f(hv.y);
            }
        }
    }
    if (t < 20) {
        float2 rr = *(const float2*)(h2r2 + (size_t)n * 80 + 40 + 2 * t);
        float2 gv = *(const float2*)(gb + 2 * t);
        float2 ov = {acc0 * iv + gv.x + rr.x, acc1 * iv + gv.y + rr.y};
        *(float2*)(out + (size_t)n * OUTC + 2 * t) = ov;
    }
}

// ---------------------------------------------------------------------------
// Launcher
// ---------------------------------------------------------------------------
extern "C" void kernel_launch(void* const* d_in, const int* in_sizes, int n_in,
                              void* d_out, int out_size, void* d_ws, size_t ws_size,
                              hipStream_t stream) {
    const float* x      = (const float*)d_in[0];
    const int*   ei     = (const int*)d_in[1];
    const float* ae_w1  = (const float*)d_in[2];
    const float* ae_b1  = (const float*)d_in[3];
    const float* ae_w2  = (const float*)d_in[4];
    const float* ae_b2  = (const float*)d_in[5];
    const float* gat1_w = (const float*)d_in[6];
    const float* g1as   = (const float*)d_in[7];
    const float* g1ad   = (const float*)d_in[8];
    const float* g1b    = (const float*)d_in[9];
    const float* gat2_w = (const float*)d_in[10];
    const float* g2as   = (const float*)d_in[11];
    const float* g2ad   = (const float*)d_in[12];
    const float* g2b    = (const float*)d_in[13];
    const float* res1_w = (const float*)d_in[14];
    const float* res1_b = (const float*)d_in[15];
    const float* res2_w = (const float*)d_in[16];
    const float* res2_b = (const float*)d_in[17];
    float* out = (float*)d_out;

    const int Nn = in_sizes[0] / 512;       // 50000 nodes
    const int E  = in_sizes[1] / 2;         // 800000 edges
    const int Etot = E + Nn;

    const int* srcA = ei;
    const int* dstA = ei + E;

    // ---- workspace layout ----
    char* W = (char*)d_ws;
    size_t off = 0;
    auto alloc = [&](size_t bytes) { char* p = W + off; off += (bytes + 255) & ~(size_t)255; return p; };

    // Region1: xb bf16 [Nn,512]; after fc1 reused as hbuf/h2r2/h2bf
    char* reg1 = alloc((size_t)Nn * 512 * 2);
    unsigned short* xb = (unsigned short*)reg1;
    float* hbuf = (float*)reg1;                                  // [Nn,128] f32
    float* h2r2 = (float*)(reg1 + (size_t)Nn * 128 * 4);         // [Nn,80] f32
    unsigned short* h2bf = (unsigned short*)(reg1 + (size_t)Nn * 208 * 4); // [Nn,40]

    // Region2: y1b bf16 [Nn,256]; after fc2 reused as r1 f32 [Nn,128]
    char* reg2 = alloc((size_t)Nn * 256 * 2);
    unsigned short* y1b = (unsigned short*)reg2;
    float* r1 = (float*)reg2;

    unsigned short* xeb = (unsigned short*)alloc((size_t)Nn * 256 * 2);
    unsigned short* h1b = (unsigned short*)alloc((size_t)Nn * 128 * 2);

    short* w1T = (short*)alloc(256 * 512 * 2);
    short* w2T = (short*)alloc(256 * 256 * 2);
    short* wc1 = (short*)alloc(256 * 256 * 2);
    float* wc2 = (float*)alloc(128 * 80 * 4);
    float* cb2 = (float*)alloc(128 * 4);
    float* as1 = (float*)alloc((size_t)Nn * HEADS * 4);
    float* ad1 = (float*)alloc((size_t)Nn * HEADS * 4);
    float* as2 = (float*)alloc((size_t)Nn * 4);
    float* ad2 = (float*)alloc((size_t)Nn * 4);
    float* m1  = (float*)alloc((size_t)Nn * HEADS * 4);
    float* iv1 = (float*)alloc((size_t)Nn * HEADS * 4);
    float* m2  = (float*)alloc((size_t)Nn * 4);
    float* iv2 = (float*)alloc((size_t)Nn * 4);
    float* va1 = (float*)alloc((size_t)Etot * HEADS * 4);     // 13.6 MB
    float* va2 = (float*)alloc((size_t)Etot * 4);             // 3.4 MB
    int* deg  = (int*)alloc((size_t)Nn * 4);
    int* offs = (int*)alloc((size_t)(Nn + 1) * 4);
    int* cur  = (int*)alloc((size_t)Nn * 4);
    int* part = (int*)alloc(256 * 4);
    int* csr  = (int*)alloc((size_t)Etot * 4);

    // ---- weight prep (fused) ----
    {
        int total = 131072 + 65536 + 65536 + 128 * 80 + 80;
        wprep<<<(total + 255) / 256, 256, 0, stream>>>(
            ae_w1, ae_w2, gat1_w, res1_w, gat2_w, res2_w, res2_b,
            w1T, w2T, wc1, wc2, cb2);
    }

    // ---- CSR build ----
    hipMemsetAsync(deg, 0, (size_t)Nn * sizeof(int), stream);
    count_deg<<<(E + 255) / 256, 256, 0, stream>>>(dstA, E, deg);
    int nb = (Nn + 1023) / 1024;
    scan_part<<<nb, 256, 0, stream>>>(deg, Nn, part);
    scan_base<<<1, 64, 0, stream>>>(part, nb, offs);
    scan_final<<<nb, 256, 0, stream>>>(deg, Nn, part, offs, cur);
    scatter_k<<<(E + 255) / 256, 256, 0, stream>>>(srcA, dstA, E, cur, csr);
    selfloop_k<<<(Nn + 255) / 256, 256, 0, stream>>>(offs, csr, Nn);

    // ---- x -> bf16 ----
    long xtotal = (long)Nn * 512;
    x2bf<<<(int)((xtotal / 8 + 255) / 256), 256, 0, stream>>>(x, (unsigned int*)xb, xtotal);

    const int gy = (Nn + 127) / 128;   // 391

    // ---- fc1 / fc2 / gatres1 ----
    gemm2<0><<<dim3(2, gy), 256, 0, stream>>>(
        (const short*)xb, w1T, ae_b1, y1b, nullptr, Nn, 256, 512);
    gemm2<0><<<dim3(2, gy), 256, 0, stream>>>(
        (const short*)y1b, w2T, ae_b2, xeb, nullptr, Nn, 256, 256);
    gemm2<1><<<dim3(2, gy), 256, 0, stream>>>(
        (const short*)xeb, wc1, nullptr, h1b, r1, Nn, 256, 256);

    // ---- layer-1 attention path ----
    att1<<<(Nn * HEADS + 255) / 256, 256, 0, stream>>>(h1b, g1as, g1ad, as1, ad1, Nn);
    maxden1<<<(Nn + 3) / 4, 256, 0, stream>>>(as1, ad1, offs, csr, va1, m1, iv1, Nn);
    gat1_agg<<<(Nn + 3) / 4, 256, 0, stream>>>(h1b, r1, va1, m1, iv1, offs, csr, g1b, res1_b, hbuf, Nn);

    // ---- gatres2 (f32) ----
    gemm_bias<<<dim3(2, (Nn + 63) / 64), 256, 0, stream>>>(hbuf, wc2, cb2, h2r2, h2bf, Nn, 80, 128);

    // ---- layer-2 attention path ----
    att2<<<(Nn + 255) / 256, 256, 0, stream>>>(h2r2, g2as, g2ad, as2, ad2, Nn);
    maxden2<<<(Nn + 3) / 4, 256, 0, stream>>>(as2, ad2, offs, csr, va2, m2, iv2, Nn);
    gat2_agg<<<(Nn + 3) / 4, 256, 0, stream>>>(h2bf, h2r2, va2, m2, iv2, offs, csr, g2b, out, Nn);
}